// Round 1
// baseline (619.397 us; speedup 1.0000x reference)
//
#include <hip/hip_runtime.h>
#include <cstdint>

constexpr int kDM = 2048;   // d_model
constexpr int kNH = 16;     // heads
constexpr int kDH = 128;    // head dim
constexpr int kS  = 2048;   // seq
constexpr int kM  = 4096;   // B*S rows

typedef __bf16 bf16x8 __attribute__((ext_vector_type(8)));
typedef float  f32x4  __attribute__((ext_vector_type(4)));

__device__ __forceinline__ unsigned short f2bf(float f) {
    union { float f; unsigned u; } v; v.f = f;
    unsigned u = v.u;
    u += 0x7fffu + ((u >> 16) & 1u);   // RNE
    return (unsigned short)(u >> 16);
}
__device__ __forceinline__ float bf2f(unsigned short b) {
    union { unsigned u; float f; } v; v.u = ((unsigned)b) << 16;
    return v.f;
}
// async global->LDS, 16B per lane, LDS dest = wave-uniform base + lane*16
__device__ __forceinline__ void load_lds16(const void* g, void* l) {
    auto gp = (__attribute__((address_space(1))) unsigned int*)(uintptr_t)g;
    auto lp = (__attribute__((address_space(3))) unsigned int*)(uintptr_t)l;
    __builtin_amdgcn_global_load_lds(gp, lp, 16, 0, 0);
}

// ---------------- LayerNorm: fp32 in -> bf16 out ----------------
__global__ __launch_bounds__(256) void ln_kernel(const float* __restrict__ X,
        const float* __restrict__ g, const float* __restrict__ b,
        unsigned short* __restrict__ Xn) {
    const int row = blockIdx.x;
    const float* xr = X + (size_t)row * kDM;
    const float4 v0 = ((const float4*)xr)[threadIdx.x];
    const float4 v1 = ((const float4*)xr)[threadIdx.x + 256];
    float s  = v0.x + v0.y + v0.z + v0.w + v1.x + v1.y + v1.z + v1.w;
    float sq = v0.x*v0.x + v0.y*v0.y + v0.z*v0.z + v0.w*v0.w
             + v1.x*v1.x + v1.y*v1.y + v1.z*v1.z + v1.w*v1.w;
    #pragma unroll
    for (int m = 1; m < 64; m <<= 1) { s += __shfl_xor(s, m); sq += __shfl_xor(sq, m); }
    __shared__ float ls[4], lq[4];
    if ((threadIdx.x & 63) == 0) { ls[threadIdx.x >> 6] = s; lq[threadIdx.x >> 6] = sq; }
    __syncthreads();
    s  = ls[0] + ls[1] + ls[2] + ls[3];
    sq = lq[0] + lq[1] + lq[2] + lq[3];
    const float mu   = s * (1.0f / kDM);
    const float rstd = rsqrtf(sq * (1.0f / kDM) - mu * mu + 1e-5f);
    unsigned short* xo = Xn + (size_t)row * kDM;
    {
        const float4 gg = ((const float4*)g)[threadIdx.x];
        const float4 bb = ((const float4*)b)[threadIdx.x];
        ushort4 o;
        o.x = f2bf((v0.x - mu) * rstd * gg.x + bb.x);
        o.y = f2bf((v0.y - mu) * rstd * gg.y + bb.y);
        o.z = f2bf((v0.z - mu) * rstd * gg.z + bb.z);
        o.w = f2bf((v0.w - mu) * rstd * gg.w + bb.w);
        ((ushort4*)xo)[threadIdx.x] = o;
    }
    {
        const float4 gg = ((const float4*)g)[threadIdx.x + 256];
        const float4 bb = ((const float4*)b)[threadIdx.x + 256];
        ushort4 o;
        o.x = f2bf((v1.x - mu) * rstd * gg.x + bb.x);
        o.y = f2bf((v1.y - mu) * rstd * gg.y + bb.y);
        o.z = f2bf((v1.z - mu) * rstd * gg.z + bb.z);
        o.w = f2bf((v1.w - mu) * rstd * gg.w + bb.w);
        ((ushort4*)xo)[threadIdx.x + 256] = o;
    }
}

// ------------- weight transpose+cast: W[K][N] f32 -> Wt[N][K] bf16 -------------
__global__ __launch_bounds__(256) void wt_kernel(
        const float* __restrict__ W0, const float* __restrict__ W1,
        const float* __restrict__ W2, const float* __restrict__ W3,
        unsigned short* __restrict__ T0, unsigned short* __restrict__ T1,
        unsigned short* __restrict__ T2, unsigned short* __restrict__ T3) {
    const float* W; unsigned short* T;
    switch (blockIdx.z) {
        case 0:  W = W0; T = T0; break;
        case 1:  W = W1; T = T1; break;
        case 2:  W = W2; T = T2; break;
        default: W = W3; T = T3; break;
    }
    __shared__ float tile[32][33];
    const int tx = threadIdx.x & 31, ty = threadIdx.x >> 5;
    const int r0 = blockIdx.y * 32, c0 = blockIdx.x * 32;
    #pragma unroll
    for (int i = 0; i < 4; ++i)
        tile[ty + i * 8][tx] = W[(size_t)(r0 + ty + i * 8) * kDM + c0 + tx];
    __syncthreads();
    #pragma unroll
    for (int i = 0; i < 4; ++i)
        T[(size_t)(c0 + ty + i * 8) * kDM + r0 + tx] = f2bf(tile[tx][ty + i * 8]);
}

// ------------- GEMM: C[M,N] = A[M,K]bf16 @ Wt[N,K]^T bf16 + bias -------------
// mode 0: fp32 row-major out.  mode 1: bf16 out as [B,H,S,Dh].  mode 2: bf16 out as [B,H,Dh,S].
// scale applies to (acc + bias).
__global__ __launch_bounds__(256) void gemm_kernel(
        const unsigned short* __restrict__ A, const unsigned short* __restrict__ Bt,
        const float* __restrict__ bias, void* __restrict__ Cout,
        const float scale, const int mode) {
    __shared__ __align__(16) unsigned short ldsA[128 * 32];
    __shared__ __align__(16) unsigned short ldsB[128 * 32];
    const int m0 = blockIdx.y * 128, n0 = blockIdx.x * 128;
    const int tid = threadIdx.x, lane = tid & 63, w = tid >> 6;
    const int wm = (w >> 1) * 64, wn = (w & 1) * 64;
    const int quad = lane >> 4, l15 = lane & 15;
    f32x4 acc[4][4] = {};
    const int srow = lane >> 2, scol = (lane & 3) * 8;
    for (int k0 = 0; k0 < kDM; k0 += 32) {
        __syncthreads();
        #pragma unroll
        for (int i = 0; i < 2; ++i) {
            const int c = w + i * 4;
            const int row = c * 16 + srow;
            load_lds16(A  + (size_t)(m0 + row) * kDM + k0 + scol, ldsA + c * 512);
            load_lds16(Bt + (size_t)(n0 + row) * kDM + k0 + scol, ldsB + c * 512);
        }
        __syncthreads();
        bf16x8 af[4], bfr[4];
        #pragma unroll
        for (int mt = 0; mt < 4; ++mt)
            af[mt] = *(const bf16x8*)(ldsA + (wm + mt * 16 + l15) * 32 + quad * 8);
        #pragma unroll
        for (int nt = 0; nt < 4; ++nt)
            bfr[nt] = *(const bf16x8*)(ldsB + (wn + nt * 16 + l15) * 32 + quad * 8);
        #pragma unroll
        for (int mt = 0; mt < 4; ++mt)
            #pragma unroll
            for (int nt = 0; nt < 4; ++nt)
                acc[mt][nt] = __builtin_amdgcn_mfma_f32_16x16x32_bf16(af[mt], bfr[nt], acc[mt][nt], 0, 0, 0);
    }
    #pragma unroll
    for (int mt = 0; mt < 4; ++mt) {
        #pragma unroll
        for (int nt = 0; nt < 4; ++nt) {
            const int ng = n0 + wn + nt * 16 + l15;
            const float bv = bias[ng];
            #pragma unroll
            for (int r = 0; r < 4; ++r) {
                const int mg = m0 + wm + mt * 16 + quad * 4 + r;
                const float val = (acc[mt][nt][r] + bv) * scale;
                if (mode == 0) {
                    ((float*)Cout)[(size_t)mg * kDM + ng] = val;
                } else {
                    const int bb = mg >> 11, ss = mg & 2047;
                    const int h = ng >> 7, dh = ng & 127;
                    if (mode == 1)
                        ((unsigned short*)Cout)[((size_t)(bb * kNH + h) * kS + ss) * kDH + dh] = f2bf(val);
                    else
                        ((unsigned short*)Cout)[((size_t)(bb * kNH + h) * kDH + dh) * kS + ss] = f2bf(val);
                }
            }
        }
    }
}

// ------------- causal flash attention -------------
// Q,K: [B,H,S,Dh] bf16 (Q pre-scaled by 1/sqrt(Dh)); Vt: [B,H,Dh,S] bf16; AV out: [M, DM] bf16
__global__ __launch_bounds__(256) void attn_kernel(
        const unsigned short* __restrict__ Q, const unsigned short* __restrict__ Kk,
        const unsigned short* __restrict__ Vt, unsigned short* __restrict__ AV) {
    __shared__ __align__(16) unsigned short ldsK[64 * 128];   // [key][d]
    __shared__ __align__(16) unsigned short ldsV[128 * 64];   // [d][key]
    __shared__ __align__(16) unsigned short ldsP[4 * 32 * 64];// per-wave [row][key]
    const int qt = blockIdx.x, bh = blockIdx.y;
    const unsigned short* Qb = Q  + (size_t)bh * kS * kDH;
    const unsigned short* Kb = Kk + (size_t)bh * kS * kDH;
    const unsigned short* Vb = Vt + (size_t)bh * kDH * kS;
    const int tid = threadIdx.x, lane = tid & 63, w = tid >> 6;
    const int quad = lane >> 4, l15 = lane & 15;
    const int qrow0 = qt * 128 + w * 32;
    bf16x8 qf[2][4];
    #pragma unroll
    for (int mt = 0; mt < 2; ++mt)
        #pragma unroll
        for (int kk = 0; kk < 4; ++kk)
            qf[mt][kk] = *(const bf16x8*)(Qb + (size_t)(qrow0 + mt * 16 + l15) * kDH + kk * 32 + quad * 8);
    f32x4 accO[2][8] = {};
    float mrun[2][4], lrun[2][4];
    #pragma unroll
    for (int mt = 0; mt < 2; ++mt)
        #pragma unroll
        for (int r = 0; r < 4; ++r) { mrun[mt][r] = -3.0e38f; lrun[mt][r] = 0.f; }
    const int nkt = 2 * qt + 2;                  // 64-wide key tiles
    unsigned short* pw = ldsP + w * 2048;
    for (int kt = 0; kt < nkt; ++kt) {
        __syncthreads();
        #pragma unroll
        for (int i = 0; i < 4; ++i) {
            const int c = w * 4 + i;
            load_lds16(Kb + (size_t)(kt * 64 + c * 4 + (lane >> 4)) * kDH + l15 * 8, ldsK + c * 512);
            load_lds16(Vb + (size_t)(c * 8 + (lane >> 3)) * kS + kt * 64 + (lane & 7) * 8, ldsV + c * 512);
        }
        __syncthreads();
        if (kt * 64 > qrow0 + 31) continue;      // wave fully masked for this key tile
        f32x4 accS[2][4] = {};
        #pragma unroll
        for (int kk = 0; kk < 4; ++kk) {
            bf16x8 kf[4];
            #pragma unroll
            for (int nt = 0; nt < 4; ++nt)
                kf[nt] = *(const bf16x8*)(ldsK + (nt * 16 + l15) * 128 + kk * 32 + quad * 8);
            #pragma unroll
            for (int mt = 0; mt < 2; ++mt)
                #pragma unroll
                for (int nt = 0; nt < 4; ++nt)
                    accS[mt][nt] = __builtin_amdgcn_mfma_f32_16x16x32_bf16(qf[mt][kk], kf[nt], accS[mt][nt], 0, 0, 0);
        }
        if (kt >= 2 * qt) {                      // diagonal tiles: causal mask
            #pragma unroll
            for (int mt = 0; mt < 2; ++mt)
                #pragma unroll
                for (int nt = 0; nt < 4; ++nt)
                    #pragma unroll
                    for (int r = 0; r < 4; ++r) {
                        const int colg = kt * 64 + nt * 16 + l15;
                        const int rowg = qrow0 + mt * 16 + quad * 4 + r;
                        if (colg > rowg) accS[mt][nt][r] = -3.0e38f;
                    }
        }
        float alpha[2][4];
        #pragma unroll
        for (int mt = 0; mt < 2; ++mt) {
            #pragma unroll
            for (int r = 0; r < 4; ++r) {
                float mx = fmaxf(fmaxf(accS[mt][0][r], accS[mt][1][r]),
                                 fmaxf(accS[mt][2][r], accS[mt][3][r]));
                mx = fmaxf(mx, __shfl_xor(mx, 1));
                mx = fmaxf(mx, __shfl_xor(mx, 2));
                mx = fmaxf(mx, __shfl_xor(mx, 4));
                mx = fmaxf(mx, __shfl_xor(mx, 8));
                const float mnew = fmaxf(mrun[mt][r], mx);
                const float al = __expf(mrun[mt][r] - mnew);
                float rs = 0.f;
                const int prow = (mt * 16 + quad * 4 + r) * 64;
                #pragma unroll
                for (int nt = 0; nt < 4; ++nt) {
                    const float p = __expf(accS[mt][nt][r] - mnew);
                    const unsigned short pb = f2bf(p);
                    pw[prow + nt * 16 + l15] = pb;
                    rs += bf2f(pb);              // l consistent with bf16 P fed to PV
                }
                rs += __shfl_xor(rs, 1);
                rs += __shfl_xor(rs, 2);
                rs += __shfl_xor(rs, 4);
                rs += __shfl_xor(rs, 8);
                lrun[mt][r] = lrun[mt][r] * al + rs;
                mrun[mt][r] = mnew;
                alpha[mt][r] = al;
            }
        }
        #pragma unroll
        for (int mt = 0; mt < 2; ++mt)
            #pragma unroll
            for (int dt = 0; dt < 8; ++dt)
                #pragma unroll
                for (int r = 0; r < 4; ++r)
                    accO[mt][dt][r] *= alpha[mt][r];
        asm volatile("s_waitcnt lgkmcnt(0)" ::: "memory");  // P writes -> P reads (same wave)
        #pragma unroll
        for (int kk = 0; kk < 2; ++kk) {
            bf16x8 pa[2];
            #pragma unroll
            for (int mt = 0; mt < 2; ++mt)
                pa[mt] = *(const bf16x8*)(pw + (mt * 16 + l15) * 64 + kk * 32 + quad * 8);
            #pragma unroll
            for (int dt = 0; dt < 8; ++dt) {
                const bf16x8 vf = *(const bf16x8*)(ldsV + (dt * 16 + l15) * 64 + kk * 32 + quad * 8);
                #pragma unroll
                for (int mt = 0; mt < 2; ++mt)
                    accO[mt][dt] = __builtin_amdgcn_mfma_f32_16x16x32_bf16(pa[mt], vf, accO[mt][dt], 0, 0, 0);
            }
        }
    }
    const int bb = bh >> 4, h = bh & 15;
    #pragma unroll
    for (int mt = 0; mt < 2; ++mt)
        #pragma unroll
        for (int r = 0; r < 4; ++r) {
            const float inv = 1.0f / lrun[mt][r];
            const size_t rowg = (size_t)bb * kS + qrow0 + mt * 16 + quad * 4 + r;
            #pragma unroll
            for (int dt = 0; dt < 8; ++dt)
                AV[rowg * kDM + h * kDH + dt * 16 + l15] = f2bf(accO[mt][dt][r] * inv);
        }
}

extern "C" void kernel_launch(void* const* d_in, const int* in_sizes, int n_in,
                              void* d_out, int out_size, void* d_ws, size_t ws_size,
                              hipStream_t stream) {
    const float* X   = (const float*)d_in[0];
    const float* lng = (const float*)d_in[1];
    const float* lnb = (const float*)d_in[2];
    const float* Wq  = (const float*)d_in[3];
    const float* bq  = (const float*)d_in[4];
    const float* Wk  = (const float*)d_in[5];
    const float* bk  = (const float*)d_in[6];
    const float* Wv  = (const float*)d_in[7];
    const float* bv  = (const float*)d_in[8];
    const float* Wo  = (const float*)d_in[9];
    const float* bo  = (const float*)d_in[10];
    float* out = (float*)d_out;

    char* p = (char*)d_ws;
    unsigned short* Xn  = (unsigned short*)p; p += (size_t)kM * kDM * 2;
    unsigned short* Wqt = (unsigned short*)p; p += (size_t)kDM * kDM * 2;
    unsigned short* Wkt = (unsigned short*)p; p += (size_t)kDM * kDM * 2;
    unsigned short* Wvt = (unsigned short*)p; p += (size_t)kDM * kDM * 2;
    unsigned short* Wot = (unsigned short*)p; p += (size_t)kDM * kDM * 2;
    unsigned short* Qb  = (unsigned short*)p; p += (size_t)kM * kDM * 2;
    unsigned short* Kb  = (unsigned short*)p; p += (size_t)kM * kDM * 2;
    unsigned short* Vtb = (unsigned short*)p; p += (size_t)kM * kDM * 2;
    unsigned short* AV  = (unsigned short*)p; p += (size_t)kM * kDM * 2;

    ln_kernel<<<dim3(kM), dim3(256), 0, stream>>>(X, lng, lnb, Xn);
    wt_kernel<<<dim3(64, 64, 4), dim3(256), 0, stream>>>(Wq, Wk, Wv, Wo, Wqt, Wkt, Wvt, Wot);
    gemm_kernel<<<dim3(16, 32), dim3(256), 0, stream>>>(Xn, Wqt, bq, Qb, 0.088388347648318447f, 1);
    gemm_kernel<<<dim3(16, 32), dim3(256), 0, stream>>>(Xn, Wkt, bk, Kb, 1.0f, 1);
    gemm_kernel<<<dim3(16, 32), dim3(256), 0, stream>>>(Xn, Wvt, bv, Vtb, 1.0f, 2);
    attn_kernel<<<dim3(16, 32), dim3(256), 0, stream>>>(Qb, Kb, Vtb, AV);
    gemm_kernel<<<dim3(16, 32), dim3(256), 0, stream>>>(AV, Wot, bo, out, 1.0f, 0);
}

// Round 2
// 450.733 us; speedup vs baseline: 1.3742x; 1.3742x over previous
//
#include <hip/hip_runtime.h>
#include <cstdint>

constexpr int kDM = 2048;   // d_model
constexpr int kNH = 16;     // heads
constexpr int kDH = 128;    // head dim
constexpr int kS  = 2048;   // seq
constexpr int kM  = 4096;   // B*S rows

typedef __bf16 bf16x8 __attribute__((ext_vector_type(8)));
typedef float  f32x4  __attribute__((ext_vector_type(4)));

__device__ __forceinline__ unsigned short f2bf(float f) {
    union { float f; unsigned u; } v; v.f = f;
    unsigned u = v.u;
    u += 0x7fffu + ((u >> 16) & 1u);   // RNE
    return (unsigned short)(u >> 16);
}
__device__ __forceinline__ float bf2f(unsigned short b) {
    union { unsigned u; float f; } v; v.u = ((unsigned)b) << 16;
    return v.f;
}
__device__ __forceinline__ float fast_exp2(float x) {
#if __has_builtin(__builtin_amdgcn_exp2f)
    return __builtin_amdgcn_exp2f(x);
#else
    return exp2f(x);
#endif
}
// async global->LDS, 16B per lane, LDS dest = wave-uniform base + lane*16
__device__ __forceinline__ void load_lds16(const void* g, void* l) {
    auto gp = (__attribute__((address_space(1))) unsigned int*)(uintptr_t)g;
    auto lp = (__attribute__((address_space(3))) unsigned int*)(uintptr_t)l;
    __builtin_amdgcn_global_load_lds(gp, lp, 16, 0, 0);
}

// ---------------- LayerNorm: fp32 in -> bf16 out ----------------
__global__ __launch_bounds__(256) void ln_kernel(const float* __restrict__ X,
        const float* __restrict__ g, const float* __restrict__ b,
        unsigned short* __restrict__ Xn) {
    const int row = blockIdx.x;
    const float* xr = X + (size_t)row * kDM;
    const float4 v0 = ((const float4*)xr)[threadIdx.x];
    const float4 v1 = ((const float4*)xr)[threadIdx.x + 256];
    float s  = v0.x + v0.y + v0.z + v0.w + v1.x + v1.y + v1.z + v1.w;
    float sq = v0.x*v0.x + v0.y*v0.y + v0.z*v0.z + v0.w*v0.w
             + v1.x*v1.x + v1.y*v1.y + v1.z*v1.z + v1.w*v1.w;
    #pragma unroll
    for (int m = 1; m < 64; m <<= 1) { s += __shfl_xor(s, m); sq += __shfl_xor(sq, m); }
    __shared__ float ls[4], lq[4];
    if ((threadIdx.x & 63) == 0) { ls[threadIdx.x >> 6] = s; lq[threadIdx.x >> 6] = sq; }
    __syncthreads();
    s  = ls[0] + ls[1] + ls[2] + ls[3];
    sq = lq[0] + lq[1] + lq[2] + lq[3];
    const float mu   = s * (1.0f / kDM);
    const float rstd = rsqrtf(sq * (1.0f / kDM) - mu * mu + 1e-5f);
    unsigned short* xo = Xn + (size_t)row * kDM;
    {
        const float4 gg = ((const float4*)g)[threadIdx.x];
        const float4 bb = ((const float4*)b)[threadIdx.x];
        ushort4 o;
        o.x = f2bf((v0.x - mu) * rstd * gg.x + bb.x);
        o.y = f2bf((v0.y - mu) * rstd * gg.y + bb.y);
        o.z = f2bf((v0.z - mu) * rstd * gg.z + bb.z);
        o.w = f2bf((v0.w - mu) * rstd * gg.w + bb.w);
        ((ushort4*)xo)[threadIdx.x] = o;
    }
    {
        const float4 gg = ((const float4*)g)[threadIdx.x + 256];
        const float4 bb = ((const float4*)b)[threadIdx.x + 256];
        ushort4 o;
        o.x = f2bf((v1.x - mu) * rstd * gg.x + bb.x);
        o.y = f2bf((v1.y - mu) * rstd * gg.y + bb.y);
        o.z = f2bf((v1.z - mu) * rstd * gg.z + bb.z);
        o.w = f2bf((v1.w - mu) * rstd * gg.w + bb.w);
        ((ushort4*)xo)[threadIdx.x + 256] = o;
    }
}

// ------------- weight transpose+cast: W[K][N] f32 -> Wt[N][K] bf16 -------------
__global__ __launch_bounds__(256) void wt_kernel(
        const float* __restrict__ W0, const float* __restrict__ W1,
        const float* __restrict__ W2, const float* __restrict__ W3,
        unsigned short* __restrict__ T0, unsigned short* __restrict__ T1,
        unsigned short* __restrict__ T2, unsigned short* __restrict__ T3) {
    const float* W; unsigned short* T;
    switch (blockIdx.z) {
        case 0:  W = W0; T = T0; break;
        case 1:  W = W1; T = T1; break;
        case 2:  W = W2; T = T2; break;
        default: W = W3; T = T3; break;
    }
    __shared__ float tile[32][33];
    const int tx = threadIdx.x & 31, ty = threadIdx.x >> 5;
    const int r0 = blockIdx.y * 32, c0 = blockIdx.x * 32;
    #pragma unroll
    for (int i = 0; i < 4; ++i)
        tile[ty + i * 8][tx] = W[(size_t)(r0 + ty + i * 8) * kDM + c0 + tx];
    __syncthreads();
    #pragma unroll
    for (int i = 0; i < 4; ++i)
        T[(size_t)(c0 + ty + i * 8) * kDM + r0 + tx] = f2bf(tile[tx][ty + i * 8]);
}

// --- V transpose: [bh][s][dh] bf16 -> [bh][dh][s] bf16, 64x64 tiles ---
__global__ __launch_bounds__(256) void vtr_kernel(const unsigned short* __restrict__ Vin,
                                                  unsigned short* __restrict__ Vout) {
    __shared__ __align__(16) unsigned short tile[64 * 72];
    const int bhz = blockIdx.z;
    const int s0 = blockIdx.x * 64, d0 = blockIdx.y * 64;
    const int t = threadIdx.x;
    const unsigned short* src = Vin + ((size_t)bhz * kS + s0) * kDH + d0;
    #pragma unroll
    for (int i = 0; i < 2; ++i) {
        const int r = (t >> 3) + 32 * i;   // s-row within tile
        const int g = t & 7;               // 8-short granule along d
        *(uint4*)(tile + r * 72 + g * 8) = *(const uint4*)(src + (size_t)r * kDH + g * 8);
    }
    __syncthreads();
    unsigned short* dst = Vout + ((size_t)bhz * kDH + d0) * kS + s0;
    #pragma unroll
    for (int i = 0; i < 2; ++i) {
        const int d = (t >> 3) + 32 * i;   // d-row of output
        const int sg = t & 7;              // 8-short granule along s
        union { unsigned short u[8]; uint4 v; } o;
        #pragma unroll
        for (int j = 0; j < 8; ++j)
            o.u[j] = tile[(sg * 8 + j) * 72 + d];
        *(uint4*)(dst + (size_t)d * kS + sg * 8) = o.v;
    }
}

// ------------- GEMM: C[M,N] = A[M,K]bf16 @ Wt[N,K]^T bf16 + bias -------------
// mode 0: fp32 row-major out.  mode 1: bf16 out as [B,H,S,Dh].
__global__ __launch_bounds__(256) void gemm_kernel(
        const unsigned short* __restrict__ A, const unsigned short* __restrict__ Bt,
        const float* __restrict__ bias, void* __restrict__ Cout,
        const float scale, const int mode) {
    __shared__ __align__(16) unsigned short ldsA[128 * 32];
    __shared__ __align__(16) unsigned short ldsB[128 * 32];
    const int m0 = blockIdx.y * 128, n0 = blockIdx.x * 128;
    const int tid = threadIdx.x, lane = tid & 63, w = tid >> 6;
    const int wm = (w >> 1) * 64, wn = (w & 1) * 64;
    const int quad = lane >> 4, l15 = lane & 15;
    f32x4 acc[4][4] = {};
    const int srow = lane >> 2, scol = (lane & 3) * 8;
    for (int k0 = 0; k0 < kDM; k0 += 32) {
        __syncthreads();
        #pragma unroll
        for (int i = 0; i < 2; ++i) {
            const int c = w + i * 4;
            const int row = c * 16 + srow;
            load_lds16(A  + (size_t)(m0 + row) * kDM + k0 + scol, ldsA + c * 512);
            load_lds16(Bt + (size_t)(n0 + row) * kDM + k0 + scol, ldsB + c * 512);
        }
        __syncthreads();
        bf16x8 af[4], bfr[4];
        #pragma unroll
        for (int mt = 0; mt < 4; ++mt)
            af[mt] = *(const bf16x8*)(ldsA + (wm + mt * 16 + l15) * 32 + quad * 8);
        #pragma unroll
        for (int nt = 0; nt < 4; ++nt)
            bfr[nt] = *(const bf16x8*)(ldsB + (wn + nt * 16 + l15) * 32 + quad * 8);
        #pragma unroll
        for (int mt = 0; mt < 4; ++mt)
            #pragma unroll
            for (int nt = 0; nt < 4; ++nt)
                acc[mt][nt] = __builtin_amdgcn_mfma_f32_16x16x32_bf16(af[mt], bfr[nt], acc[mt][nt], 0, 0, 0);
    }
    #pragma unroll
    for (int mt = 0; mt < 4; ++mt) {
        #pragma unroll
        for (int nt = 0; nt < 4; ++nt) {
            const int ng = n0 + wn + nt * 16 + l15;
            const float bv = bias[ng];
            #pragma unroll
            for (int r = 0; r < 4; ++r) {
                const int mg = m0 + wm + mt * 16 + quad * 4 + r;
                const float val = (acc[mt][nt][r] + bv) * scale;
                if (mode == 0) {
                    ((float*)Cout)[(size_t)mg * kDM + ng] = val;
                } else {
                    const int bb = mg >> 11, ss = mg & 2047;
                    const int h = ng >> 7, dh = ng & 127;
                    ((unsigned short*)Cout)[((size_t)(bb * kNH + h) * kS + ss) * kDH + dh] = f2bf(val);
                }
            }
        }
    }
}

// ------------- causal flash attention (64-row Q tiles, swizzled LDS) -------------
// Q,K: [B,H,S,Dh] bf16 (Q pre-scaled by log2e/sqrt(Dh)); Vt: [B,H,Dh,S] bf16;
// AV out: [M, DM] bf16
__global__ __launch_bounds__(256, 4) void attn_kernel(
        const unsigned short* __restrict__ Q, const unsigned short* __restrict__ Kk,
        const unsigned short* __restrict__ Vt, unsigned short* __restrict__ AV) {
    __shared__ __align__(16) unsigned short ldsK[64 * 128];   // swizzled [key][d]
    __shared__ __align__(16) unsigned short ldsV[128 * 64];   // swizzled [d][key]
    __shared__ __align__(16) unsigned short ldsP[4 * 16 * 64];// per-wave swizzled [row][key]
    const int bh = blockIdx.x;
    const int qt = (int)gridDim.y - 1 - (int)blockIdx.y;      // long blocks first
    const unsigned short* Qb = Q  + (size_t)bh * kS * kDH;
    const unsigned short* Kb = Kk + (size_t)bh * kS * kDH;
    const unsigned short* Vb = Vt + (size_t)bh * kDH * kS;
    const int tid = threadIdx.x, lane = tid & 63, w = tid >> 6;
    const int quad = lane >> 4, l15 = lane & 15;
    const int qrow0 = qt * 64 + w * 16;                       // wave owns 16 Q rows
    bf16x8 qf[4];
    #pragma unroll
    for (int kk = 0; kk < 4; ++kk)
        qf[kk] = *(const bf16x8*)(Qb + (size_t)(qrow0 + l15) * kDH + kk * 32 + quad * 8);
    f32x4 accO[8] = {};
    float mrun[4], lrun[4];
    #pragma unroll
    for (int r = 0; r < 4; ++r) { mrun[r] = -3.0e38f; lrun[r] = 0.f; }
    // precomputed swizzled staging offsets (chunk (row,g) at pos row*G + (g ^ (row&(G-1))))
    int kSrc[4], vSrc[4], ldst[4];
    #pragma unroll
    for (int i = 0; i < 4; ++i) {
        const int c = w * 4 + i;
        const int rK = c * 4 + (lane >> 4);
        const int gK = (lane & 15) ^ (rK & 15);
        kSrc[i] = rK * kDH + gK * 8;
        const int dV = c * 8 + (lane >> 3);
        const int gV = (lane & 7) ^ (dV & 7);
        vSrc[i] = dV * kS + gV * 8;
        ldst[i] = c * 512;
    }
    unsigned short* pw = ldsP + w * 1024;
    for (int kt = 0; kt <= qt; ++kt) {
        __syncthreads();
        #pragma unroll
        for (int i = 0; i < 4; ++i) {
            load_lds16(Kb + (size_t)kt * (64 * kDH) + kSrc[i], ldsK + ldst[i]);
            load_lds16(Vb + kt * 64 + vSrc[i], ldsV + ldst[i]);
        }
        __syncthreads();
        f32x4 accS[4] = {};
        #pragma unroll
        for (int kk = 0; kk < 4; ++kk) {
            bf16x8 kf[4];
            #pragma unroll
            for (int nt = 0; nt < 4; ++nt)
                kf[nt] = *(const bf16x8*)(ldsK + (nt * 16 + l15) * 128 + (((kk * 4 + quad) ^ l15) << 3));
            #pragma unroll
            for (int nt = 0; nt < 4; ++nt)
                accS[nt] = __builtin_amdgcn_mfma_f32_16x16x32_bf16(qf[kk], kf[nt], accS[nt], 0, 0, 0);
        }
        if (kt == qt) {                       // diagonal tile: causal mask
            #pragma unroll
            for (int nt = 0; nt < 4; ++nt) {
                const int colg = nt * 16 + l15;
                #pragma unroll
                for (int r = 0; r < 4; ++r) {
                    const int rowg = w * 16 + quad * 4 + r;
                    if (colg > rowg) accS[nt][r] = -3.0e38f;
                }
            }
        }
        float alpha[4];
        #pragma unroll
        for (int r = 0; r < 4; ++r) {
            float mx = fmaxf(fmaxf(accS[0][r], accS[1][r]), fmaxf(accS[2][r], accS[3][r]));
            mx = fmaxf(mx, __shfl_xor(mx, 1));
            mx = fmaxf(mx, __shfl_xor(mx, 2));
            mx = fmaxf(mx, __shfl_xor(mx, 4));
            mx = fmaxf(mx, __shfl_xor(mx, 8));
            const float mnew = fmaxf(mrun[r], mx);
            const float al = fast_exp2(mrun[r] - mnew);
            const int rho = quad * 4 + r;
            float rs = 0.f;
            #pragma unroll
            for (int nt = 0; nt < 4; ++nt) {
                const float p = fast_exp2(accS[nt][r] - mnew);
                const unsigned short pb = f2bf(p);
                const int gP = (nt * 2 + (l15 >> 3)) ^ (rho & 7);
                pw[((rho * 8 + gP) << 3) + (l15 & 7)] = pb;
                rs += bf2f(pb);               // keep l consistent with bf16 P
            }
            rs += __shfl_xor(rs, 1);
            rs += __shfl_xor(rs, 2);
            rs += __shfl_xor(rs, 4);
            rs += __shfl_xor(rs, 8);
            lrun[r] = lrun[r] * al + rs;
            mrun[r] = mnew;
            alpha[r] = al;
        }
        #pragma unroll
        for (int dt = 0; dt < 8; ++dt)
            #pragma unroll
            for (int r = 0; r < 4; ++r)
                accO[dt][r] *= alpha[r];
        asm volatile("s_waitcnt lgkmcnt(0)" ::: "memory");  // P writes -> P reads (same wave)
        #pragma unroll
        for (int kk = 0; kk < 2; ++kk) {
            const bf16x8 pa = *(const bf16x8*)(pw + ((l15 * 8 + ((kk * 4 + quad) ^ (l15 & 7))) << 3));
            #pragma unroll
            for (int dt = 0; dt < 8; ++dt) {
                const bf16x8 vf = *(const bf16x8*)(ldsV + (dt * 16 + l15) * 64 + (((kk * 4 + quad) ^ (l15 & 7)) << 3));
                accO[dt] = __builtin_amdgcn_mfma_f32_16x16x32_bf16(pa, vf, accO[dt], 0, 0, 0);
            }
        }
    }
    const int bb = bh >> 4, h = bh & 15;
    #pragma unroll
    for (int r = 0; r < 4; ++r) {
        const float inv = 1.0f / lrun[r];
        unsigned short* orow = AV + ((size_t)bb * kS + qrow0 + quad * 4 + r) * kDM + h * kDH;
        #pragma unroll
        for (int dt = 0; dt < 8; ++dt)
            orow[dt * 16 + l15] = f2bf(accO[dt][r] * inv);
    }
}

extern "C" void kernel_launch(void* const* d_in, const int* in_sizes, int n_in,
                              void* d_out, int out_size, void* d_ws, size_t ws_size,
                              hipStream_t stream) {
    const float* X   = (const float*)d_in[0];
    const float* lng = (const float*)d_in[1];
    const float* lnb = (const float*)d_in[2];
    const float* Wq  = (const float*)d_in[3];
    const float* bq  = (const float*)d_in[4];
    const float* Wk  = (const float*)d_in[5];
    const float* bk  = (const float*)d_in[6];
    const float* Wv  = (const float*)d_in[7];
    const float* bv  = (const float*)d_in[8];
    const float* Wo  = (const float*)d_in[9];
    const float* bo  = (const float*)d_in[10];
    float* out = (float*)d_out;

    char* p = (char*)d_ws;
    unsigned short* Xn  = (unsigned short*)p; p += (size_t)kM * kDM * 2;
    unsigned short* Wqt = (unsigned short*)p; p += (size_t)kDM * kDM * 2;
    unsigned short* Wkt = (unsigned short*)p; p += (size_t)kDM * kDM * 2;
    unsigned short* Wvt = (unsigned short*)p; p += (size_t)kDM * kDM * 2;
    unsigned short* Wot = (unsigned short*)p; p += (size_t)kDM * kDM * 2;
    unsigned short* Qb  = (unsigned short*)p; p += (size_t)kM * kDM * 2;
    unsigned short* Kb  = (unsigned short*)p; p += (size_t)kM * kDM * 2;
    unsigned short* Vtb = (unsigned short*)p; p += (size_t)kM * kDM * 2;
    unsigned short* AV  = (unsigned short*)p; p += (size_t)kM * kDM * 2;
    unsigned short* Vtmp = AV;   // alias: Vtmp consumed by vtr before attn writes AV

    // log2(e)/sqrt(Dh): exp2-domain softmax
    const float qscale = 0.08838834764831845f * 1.4426950408889634f;

    ln_kernel<<<dim3(kM), dim3(256), 0, stream>>>(X, lng, lnb, Xn);
    wt_kernel<<<dim3(64, 64, 4), dim3(256), 0, stream>>>(Wq, Wk, Wv, Wo, Wqt, Wkt, Wvt, Wot);
    gemm_kernel<<<dim3(16, 32), dim3(256), 0, stream>>>(Xn, Wqt, bq, Qb, qscale, 1);
    gemm_kernel<<<dim3(16, 32), dim3(256), 0, stream>>>(Xn, Wkt, bk, Kb, 1.0f, 1);
    gemm_kernel<<<dim3(16, 32), dim3(256), 0, stream>>>(Xn, Wvt, bv, Vtmp, 1.0f, 1);
    vtr_kernel<<<dim3(32, 2, 32), dim3(256), 0, stream>>>(Vtmp, Vtb);
    attn_kernel<<<dim3(32, 32), dim3(256), 0, stream>>>(Qb, Kb, Vtb, AV);
    gemm_kernel<<<dim3(16, 32), dim3(256), 0, stream>>>(AV, Wot, bo, out, 1.0f, 0);
}

// Round 3
// 403.153 us; speedup vs baseline: 1.5364x; 1.1180x over previous
//
#include <hip/hip_runtime.h>
#include <cstdint>

constexpr int kDM = 2048;   // d_model
constexpr int kNH = 16;     // heads
constexpr int kDH = 128;    // head dim
constexpr int kS  = 2048;   // seq
constexpr int kM  = 4096;   // B*S rows

typedef __bf16 bf16x8 __attribute__((ext_vector_type(8)));
typedef float  f32x4  __attribute__((ext_vector_type(4)));

__device__ __forceinline__ unsigned short f2bf(float f) {
    union { float f; unsigned u; } v; v.f = f;
    unsigned u = v.u;
    u += 0x7fffu + ((u >> 16) & 1u);   // RNE
    return (unsigned short)(u >> 16);
}
__device__ __forceinline__ float bf2f(unsigned short b) {
    union { unsigned u; float f; } v; v.u = ((unsigned)b) << 16;
    return v.f;
}
__device__ __forceinline__ float fast_exp2(float x) {
#if __has_builtin(__builtin_amdgcn_exp2f)
    return __builtin_amdgcn_exp2f(x);
#else
    return exp2f(x);
#endif
}
// async global->LDS, 16B per lane, LDS dest = wave-uniform base + lane*16
__device__ __forceinline__ void load_lds16(const void* g, void* l) {
    auto gp = (__attribute__((address_space(1))) unsigned int*)(uintptr_t)g;
    auto lp = (__attribute__((address_space(3))) unsigned int*)(uintptr_t)l;
    __builtin_amdgcn_global_load_lds(gp, lp, 16, 0, 0);
}

// ---------------- LayerNorm: fp32 in -> bf16 out ----------------
__global__ __launch_bounds__(256) void ln_kernel(const float* __restrict__ X,
        const float* __restrict__ g, const float* __restrict__ b,
        unsigned short* __restrict__ Xn) {
    const int row = blockIdx.x;
    const float* xr = X + (size_t)row * kDM;
    const float4 v0 = ((const float4*)xr)[threadIdx.x];
    const float4 v1 = ((const float4*)xr)[threadIdx.x + 256];
    float s  = v0.x + v0.y + v0.z + v0.w + v1.x + v1.y + v1.z + v1.w;
    float sq = v0.x*v0.x + v0.y*v0.y + v0.z*v0.z + v0.w*v0.w
             + v1.x*v1.x + v1.y*v1.y + v1.z*v1.z + v1.w*v1.w;
    #pragma unroll
    for (int m = 1; m < 64; m <<= 1) { s += __shfl_xor(s, m); sq += __shfl_xor(sq, m); }
    __shared__ float ls[4], lq[4];
    if ((threadIdx.x & 63) == 0) { ls[threadIdx.x >> 6] = s; lq[threadIdx.x >> 6] = sq; }
    __syncthreads();
    s  = ls[0] + ls[1] + ls[2] + ls[3];
    sq = lq[0] + lq[1] + lq[2] + lq[3];
    const float mu   = s * (1.0f / kDM);
    const float rstd = rsqrtf(sq * (1.0f / kDM) - mu * mu + 1e-5f);
    unsigned short* xo = Xn + (size_t)row * kDM;
    {
        const float4 gg = ((const float4*)g)[threadIdx.x];
        const float4 bb = ((const float4*)b)[threadIdx.x];
        ushort4 o;
        o.x = f2bf((v0.x - mu) * rstd * gg.x + bb.x);
        o.y = f2bf((v0.y - mu) * rstd * gg.y + bb.y);
        o.z = f2bf((v0.z - mu) * rstd * gg.z + bb.z);
        o.w = f2bf((v0.w - mu) * rstd * gg.w + bb.w);
        ((ushort4*)xo)[threadIdx.x] = o;
    }
    {
        const float4 gg = ((const float4*)g)[threadIdx.x + 256];
        const float4 bb = ((const float4*)b)[threadIdx.x + 256];
        ushort4 o;
        o.x = f2bf((v1.x - mu) * rstd * gg.x + bb.x);
        o.y = f2bf((v1.y - mu) * rstd * gg.y + bb.y);
        o.z = f2bf((v1.z - mu) * rstd * gg.z + bb.z);
        o.w = f2bf((v1.w - mu) * rstd * gg.w + bb.w);
        ((ushort4*)xo)[threadIdx.x + 256] = o;
    }
}

// ------------- weight transpose+cast: W[K][N] f32 -> Wt[N][K] bf16 -------------
__global__ __launch_bounds__(256) void wt_kernel(
        const float* __restrict__ W0, const float* __restrict__ W1,
        const float* __restrict__ W2, const float* __restrict__ W3,
        unsigned short* __restrict__ T0, unsigned short* __restrict__ T1,
        unsigned short* __restrict__ T2, unsigned short* __restrict__ T3) {
    const float* W; unsigned short* T;
    switch (blockIdx.z) {
        case 0:  W = W0; T = T0; break;
        case 1:  W = W1; T = T1; break;
        case 2:  W = W2; T = T2; break;
        default: W = W3; T = T3; break;
    }
    __shared__ float tile[32][33];
    const int tx = threadIdx.x & 31, ty = threadIdx.x >> 5;
    const int r0 = blockIdx.y * 32, c0 = blockIdx.x * 32;
    #pragma unroll
    for (int i = 0; i < 4; ++i)
        tile[ty + i * 8][tx] = W[(size_t)(r0 + ty + i * 8) * kDM + c0 + tx];
    __syncthreads();
    #pragma unroll
    for (int i = 0; i < 4; ++i)
        T[(size_t)(c0 + ty + i * 8) * kDM + r0 + tx] = f2bf(tile[tx][ty + i * 8]);
}

// --- bias concat: [bq|bk|bv] -> 6144 floats ---
__global__ __launch_bounds__(256) void bias_pack(const float* __restrict__ bq,
        const float* __restrict__ bk, const float* __restrict__ bv,
        float* __restrict__ o) {
    const int i = blockIdx.x * 256 + threadIdx.x;
    o[i] = (i < 2048) ? bq[i] : ((i < 4096) ? bk[i - 2048] : bv[i - 4096]);
}

// --- V transpose: [bh][s][dh] bf16 -> [bh][dh][s] bf16, 64x64 tiles ---
__global__ __launch_bounds__(256) void vtr_kernel(const unsigned short* __restrict__ Vin,
                                                  unsigned short* __restrict__ Vout) {
    __shared__ __align__(16) unsigned short tile[64 * 72];
    const int bhz = blockIdx.z;
    const int s0 = blockIdx.x * 64, d0 = blockIdx.y * 64;
    const int t = threadIdx.x;
    const unsigned short* src = Vin + ((size_t)bhz * kS + s0) * kDH + d0;
    #pragma unroll
    for (int i = 0; i < 2; ++i) {
        const int r = (t >> 3) + 32 * i;
        const int g = t & 7;
        *(uint4*)(tile + r * 72 + g * 8) = *(const uint4*)(src + (size_t)r * kDH + g * 8);
    }
    __syncthreads();
    unsigned short* dst = Vout + ((size_t)bhz * kDH + d0) * kS + s0;
    #pragma unroll
    for (int i = 0; i < 2; ++i) {
        const int d = (t >> 3) + 32 * i;
        const int sg = t & 7;
        union { unsigned short u[8]; uint4 v; } o;
        #pragma unroll
        for (int j = 0; j < 8; ++j)
            o.u[j] = tile[(sg * 8 + j) * 72 + d];
        *(uint4*)(dst + (size_t)d * kS + sg * 8) = o.v;
    }
}

// ------------- GEMM: C = A[M,K]bf16 @ Bt[N,K]^T bf16 + bias -------------
// fp32out=1: fp32 row-major to C0 (N<=2048).
// fp32out=0: bf16 [B,H,S,Dh] out; proj = n0>>11 selects C0/C1/C2; scale0 on proj 0.
__global__ __launch_bounds__(256) void gemm_kernel(
        const unsigned short* __restrict__ A, const unsigned short* __restrict__ Bt,
        const float* __restrict__ bias, void* __restrict__ C0, void* __restrict__ C1,
        void* __restrict__ C2, const float scale0, const int fp32out) {
    __shared__ __align__(16) unsigned short ldsA[128 * 32];
    __shared__ __align__(16) unsigned short ldsB[128 * 32];
    const int m0 = blockIdx.y * 128, n0 = blockIdx.x * 128;
    const int tid = threadIdx.x, lane = tid & 63, w = tid >> 6;
    const int wm = (w >> 1) * 64, wn = (w & 1) * 64;
    const int quad = lane >> 4, l15 = lane & 15;
    f32x4 acc[4][4] = {};
    const int srow = lane >> 2, scol = (lane & 3) * 8;
    for (int k0 = 0; k0 < kDM; k0 += 32) {
        __syncthreads();
        #pragma unroll
        for (int i = 0; i < 2; ++i) {
            const int c = w + i * 4;
            const int row = c * 16 + srow;
            load_lds16(A  + (size_t)(m0 + row) * kDM + k0 + scol, ldsA + c * 512);
            load_lds16(Bt + (size_t)(n0 + row) * kDM + k0 + scol, ldsB + c * 512);
        }
        __syncthreads();
        bf16x8 af[4], bfr[4];
        #pragma unroll
        for (int mt = 0; mt < 4; ++mt)
            af[mt] = *(const bf16x8*)(ldsA + (wm + mt * 16 + l15) * 32 + quad * 8);
        #pragma unroll
        for (int nt = 0; nt < 4; ++nt)
            bfr[nt] = *(const bf16x8*)(ldsB + (wn + nt * 16 + l15) * 32 + quad * 8);
        #pragma unroll
        for (int mt = 0; mt < 4; ++mt)
            #pragma unroll
            for (int nt = 0; nt < 4; ++nt)
                acc[mt][nt] = __builtin_amdgcn_mfma_f32_16x16x32_bf16(af[mt], bfr[nt], acc[mt][nt], 0, 0, 0);
    }
    const int proj = n0 >> 11;
    void* Cb = (proj == 0) ? C0 : ((proj == 1) ? C1 : C2);
    const float scl = (proj == 0) ? scale0 : 1.0f;
    #pragma unroll
    for (int mt = 0; mt < 4; ++mt) {
        #pragma unroll
        for (int nt = 0; nt < 4; ++nt) {
            const int ng = n0 + wn + nt * 16 + l15;
            const float bv = bias[ng];
            const int col = ng & 2047;
            const int h = col >> 7, dh = col & 127;
            #pragma unroll
            for (int r = 0; r < 4; ++r) {
                const int mg = m0 + wm + mt * 16 + quad * 4 + r;
                const float val = (acc[mt][nt][r] + bv) * scl;
                if (fp32out) {
                    ((float*)Cb)[(size_t)mg * kDM + ng] = val;
                } else {
                    const int bb = mg >> 11, ss = mg & 2047;
                    ((unsigned short*)Cb)[((size_t)(bb * kNH + h) * kS + ss) * kDH + dh] = f2bf(val);
                }
            }
        }
    }
}

// ------------- causal flash attention, S^T form, paired q-tiles -------------
// Q,K: [B,H,S,Dh] bf16 (Q pre-scaled by log2e/sqrt(Dh)); Vt: [B,H,Dh,S] bf16;
// AV out: [M, DM] bf16.  Block handles q-tiles pr and 31-pr (uniform 33 key-iters).
__global__ __launch_bounds__(256, 2) void attn_kernel(
        const unsigned short* __restrict__ Q, const unsigned short* __restrict__ Kk,
        const unsigned short* __restrict__ Vt, unsigned short* __restrict__ AV) {
    __shared__ __align__(16) unsigned short ldsK[64 * 128];   // swizzled [key][d]
    __shared__ __align__(16) unsigned short ldsV[128 * 64];   // swizzled [d][key]
    __shared__ __align__(16) unsigned short ldsP[4 * 16 * 64];// per-wave swizzled [q][key]
    const int bh = blockIdx.x, pr = blockIdx.y;
    const unsigned short* Qb = Q  + (size_t)bh * kS * kDH;
    const unsigned short* Kb = Kk + (size_t)bh * kS * kDH;
    const unsigned short* Vb = Vt + (size_t)bh * kDH * kS;
    const int tid = threadIdx.x, lane = tid & 63, w = tid >> 6;
    const int quad = lane >> 4, l15 = lane & 15;
    // staging offsets (source-swizzled so LDS layout is XOR-permuted)
    int kSrc[4], vSrc[4], ldst[4];
    #pragma unroll
    for (int i = 0; i < 4; ++i) {
        const int c = w * 4 + i;
        const int rK = c * 4 + (lane >> 4);
        const int gK = (lane & 15) ^ (rK & 15);
        kSrc[i] = rK * kDH + gK * 8;
        const int dV = c * 8 + (lane >> 3);
        const int gV = (lane & 7) ^ (dV & 7);
        vSrc[i] = dV * kS + gV * 8;
        ldst[i] = c * 512;
    }
    unsigned short* pw = ldsP + w * 1024;
    const int pswz = 2 * (l15 & 7);           // even XOR keeps 16B pairs intact
    const int bb = bh >> 4, h = bh & 15;
    for (int half = 0; half < 2; ++half) {
        const int qt = half ? (31 - pr) : pr;
        const int qrow0 = qt * 64 + w * 16;   // wave owns 16 q-rows
        bf16x8 qf[4];
        #pragma unroll
        for (int kk = 0; kk < 4; ++kk)
            qf[kk] = *(const bf16x8*)(Qb + (size_t)(qrow0 + l15) * kDH + kk * 32 + quad * 8);
        f32x4 accO[8] = {};
        float mrun = -3.0e38f, lrun = 0.0f;   // per-lane state for q = qrow0 + l15
        for (int kt = 0; kt <= qt; ++kt) {
            __syncthreads();
            #pragma unroll
            for (int i = 0; i < 4; ++i) {
                load_lds16(Kb + (size_t)kt * (64 * kDH) + kSrc[i], ldsK + ldst[i]);
                load_lds16(Vb + kt * 64 + vSrc[i], ldsV + ldst[i]);
            }
            __syncthreads();
            // S^T = K . Q^T : A = K-frag (m=key), B = Q-frag (n=q)
            f32x4 accS[4] = {};
            #pragma unroll
            for (int kk = 0; kk < 4; ++kk) {
                bf16x8 kf[4];
                #pragma unroll
                for (int mt = 0; mt < 4; ++mt)
                    kf[mt] = *(const bf16x8*)(ldsK + (mt * 16 + l15) * 128 + (((kk * 4 + quad) ^ l15) << 3));
                #pragma unroll
                for (int mt = 0; mt < 4; ++mt)
                    accS[mt] = __builtin_amdgcn_mfma_f32_16x16x32_bf16(kf[mt], qf[kk], accS[mt], 0, 0, 0);
            }
            if (kt == qt) {                   // diagonal: mask key_local > q_local
                const int ql = w * 16 + l15;
                #pragma unroll
                for (int mt = 0; mt < 4; ++mt)
                    #pragma unroll
                    for (int r = 0; r < 4; ++r)
                        if (mt * 16 + quad * 4 + r > ql) accS[mt][r] = -3.0e38f;
            }
            // per-lane softmax over 16 in-register keys + 2 cross-quad shuffles
            float mx = accS[0][0];
            #pragma unroll
            for (int mt = 0; mt < 4; ++mt)
                #pragma unroll
                for (int r = 0; r < 4; ++r) mx = fmaxf(mx, accS[mt][r]);
            mx = fmaxf(mx, __shfl_xor(mx, 16));
            mx = fmaxf(mx, __shfl_xor(mx, 32));
            const float mnew = fmaxf(mrun, mx);
            const float al = fast_exp2(mrun - mnew);
            float rs = 0.f;
            #pragma unroll
            for (int mt = 0; mt < 4; ++mt) {
                ushort4 pk;
                unsigned short* pe = (unsigned short*)&pk;
                #pragma unroll
                for (int r = 0; r < 4; ++r) {
                    const float p = fast_exp2(accS[mt][r] - mnew);
                    const unsigned short pb = f2bf(p);
                    pe[r] = pb;
                    rs += bf2f(pb);           // keep l consistent with bf16 P
                }
                *(ushort4*)(pw + l15 * 64 + (((mt * 4 + quad) ^ pswz) << 2)) = pk;
            }
            rs += __shfl_xor(rs, 16);
            rs += __shfl_xor(rs, 32);
            lrun = lrun * al + rs;
            mrun = mnew;
            // broadcast alpha from state-lane (l15 == quad*4+r) to accO rows
            float albr[4];
            #pragma unroll
            for (int r = 0; r < 4; ++r)
                albr[r] = __shfl(al, (lane & 48) | (quad << 2) | r);
            #pragma unroll
            for (int dt = 0; dt < 8; ++dt)
                #pragma unroll
                for (int r = 0; r < 4; ++r)
                    accO[dt][r] *= albr[r];
            asm volatile("s_waitcnt lgkmcnt(0)" ::: "memory");  // P writes visible to own wave
            // O += P . V : A = P-frag (m=q), B = V-frag (n=d)
            #pragma unroll
            for (int kk = 0; kk < 2; ++kk) {
                const bf16x8 pa = *(const bf16x8*)(pw + l15 * 64 + (((kk * 8 + quad * 2) ^ pswz) << 2));
                #pragma unroll
                for (int dt = 0; dt < 8; ++dt) {
                    const bf16x8 vf = *(const bf16x8*)(ldsV + (dt * 16 + l15) * 64 + (((kk * 4 + quad) ^ (l15 & 7)) << 3));
                    accO[dt] = __builtin_amdgcn_mfma_f32_16x16x32_bf16(pa, vf, accO[dt], 0, 0, 0);
                }
            }
        }
        float linv[4];
        #pragma unroll
        for (int r = 0; r < 4; ++r)
            linv[r] = __shfl(lrun, (lane & 48) | (quad << 2) | r);
        #pragma unroll
        for (int r = 0; r < 4; ++r) {
            const float inv = 1.0f / linv[r];
            unsigned short* orow = AV + ((size_t)bb * kS + qrow0 + quad * 4 + r) * kDM + h * kDH;
            #pragma unroll
            for (int dt = 0; dt < 8; ++dt)
                orow[dt * 16 + l15] = f2bf(accO[dt][r] * inv);
        }
    }
}

extern "C" void kernel_launch(void* const* d_in, const int* in_sizes, int n_in,
                              void* d_out, int out_size, void* d_ws, size_t ws_size,
                              hipStream_t stream) {
    const float* X   = (const float*)d_in[0];
    const float* lng = (const float*)d_in[1];
    const float* lnb = (const float*)d_in[2];
    const float* Wq  = (const float*)d_in[3];
    const float* bq  = (const float*)d_in[4];
    const float* Wk  = (const float*)d_in[5];
    const float* bk  = (const float*)d_in[6];
    const float* Wv  = (const float*)d_in[7];
    const float* bv  = (const float*)d_in[8];
    const float* Wo  = (const float*)d_in[9];
    const float* bo  = (const float*)d_in[10];
    float* out = (float*)d_out;

    char* p = (char*)d_ws;
    unsigned short* Xn  = (unsigned short*)p; p += (size_t)kM * kDM * 2;
    unsigned short* Wqt = (unsigned short*)p; p += (size_t)kDM * kDM * 2;  // Wq|Wk|Wv contiguous
    unsigned short* Wkt = (unsigned short*)p; p += (size_t)kDM * kDM * 2;
    unsigned short* Wvt = (unsigned short*)p; p += (size_t)kDM * kDM * 2;
    unsigned short* Wot = (unsigned short*)p; p += (size_t)kDM * kDM * 2;
    unsigned short* Qb  = (unsigned short*)p; p += (size_t)kM * kDM * 2;
    unsigned short* Kb  = (unsigned short*)p; p += (size_t)kM * kDM * 2;
    unsigned short* Vtb = (unsigned short*)p; p += (size_t)kM * kDM * 2;
    unsigned short* AV  = (unsigned short*)p; p += (size_t)kM * kDM * 2;
    unsigned short* Vtmp = AV;        // alias: consumed by vtr before attn writes AV
    float* biasc = (float*)Vtb;       // alias: consumed by qkv-gemm before vtr writes Vtb

    // log2(e)/sqrt(Dh): exp2-domain softmax
    const float qscale = 0.08838834764831845f * 1.4426950408889634f;

    ln_kernel<<<dim3(kM), dim3(256), 0, stream>>>(X, lng, lnb, Xn);
    wt_kernel<<<dim3(64, 64, 4), dim3(256), 0, stream>>>(Wq, Wk, Wv, Wo, Wqt, Wkt, Wvt, Wot);
    bias_pack<<<dim3(24), dim3(256), 0, stream>>>(bq, bk, bv, biasc);
    // fused QKV GEMM: N = 6144 over concatenated [Wqt|Wkt|Wvt]
    gemm_kernel<<<dim3(48, 32), dim3(256), 0, stream>>>(Xn, Wqt, biasc, Qb, Kb, Vtmp, qscale, 0);
    vtr_kernel<<<dim3(32, 2, 32), dim3(256), 0, stream>>>(Vtmp, Vtb);
    attn_kernel<<<dim3(32, 16), dim3(256), 0, stream>>>(Qb, Kb, Vtb, AV);
    gemm_kernel<<<dim3(16, 32), dim3(256), 0, stream>>>(AV, Wot, bo, out, out, out, 1.0f, 1);
}

// Round 4
// 393.884 us; speedup vs baseline: 1.5725x; 1.0235x over previous
//
#include <hip/hip_runtime.h>
#include <cstdint>

constexpr int kDM = 2048;   // d_model
constexpr int kNH = 16;     // heads
constexpr int kDH = 128;    // head dim
constexpr int kS  = 2048;   // seq
constexpr int kM  = 4096;   // B*S rows

typedef __bf16 bf16x8 __attribute__((ext_vector_type(8)));
typedef float  f32x4  __attribute__((ext_vector_type(4)));

__device__ __forceinline__ unsigned short f2bf(float f) {
    union { float f; unsigned u; } v; v.f = f;
    unsigned u = v.u;
    u += 0x7fffu + ((u >> 16) & 1u);   // RNE
    return (unsigned short)(u >> 16);
}
__device__ __forceinline__ float bf2f(unsigned short b) {
    union { unsigned u; float f; } v; v.u = ((unsigned)b) << 16;
    return v.f;
}
__device__ __forceinline__ float fast_exp2(float x) {
#if __has_builtin(__builtin_amdgcn_exp2f)
    return __builtin_amdgcn_exp2f(x);
#else
    return exp2f(x);
#endif
}
// async global->LDS, 16B per lane, LDS dest = wave-uniform base + lane*16
__device__ __forceinline__ void load_lds16(const void* g, void* l) {
    auto gp = (__attribute__((address_space(1))) unsigned int*)(uintptr_t)g;
    auto lp = (__attribute__((address_space(3))) unsigned int*)(uintptr_t)l;
    __builtin_amdgcn_global_load_lds(gp, lp, 16, 0, 0);
}

// ---------------- LayerNorm: fp32 in -> bf16 out ----------------
__global__ __launch_bounds__(256) void ln_kernel(const float* __restrict__ X,
        const float* __restrict__ g, const float* __restrict__ b,
        unsigned short* __restrict__ Xn) {
    const int row = blockIdx.x;
    const float* xr = X + (size_t)row * kDM;
    const float4 v0 = ((const float4*)xr)[threadIdx.x];
    const float4 v1 = ((const float4*)xr)[threadIdx.x + 256];
    float s  = v0.x + v0.y + v0.z + v0.w + v1.x + v1.y + v1.z + v1.w;
    float sq = v0.x*v0.x + v0.y*v0.y + v0.z*v0.z + v0.w*v0.w
             + v1.x*v1.x + v1.y*v1.y + v1.z*v1.z + v1.w*v1.w;
    #pragma unroll
    for (int m = 1; m < 64; m <<= 1) { s += __shfl_xor(s, m); sq += __shfl_xor(sq, m); }
    __shared__ float ls[4], lq[4];
    if ((threadIdx.x & 63) == 0) { ls[threadIdx.x >> 6] = s; lq[threadIdx.x >> 6] = sq; }
    __syncthreads();
    s  = ls[0] + ls[1] + ls[2] + ls[3];
    sq = lq[0] + lq[1] + lq[2] + lq[3];
    const float mu   = s * (1.0f / kDM);
    const float rstd = rsqrtf(sq * (1.0f / kDM) - mu * mu + 1e-5f);
    unsigned short* xo = Xn + (size_t)row * kDM;
    {
        const float4 gg = ((const float4*)g)[threadIdx.x];
        const float4 bb = ((const float4*)b)[threadIdx.x];
        ushort4 o;
        o.x = f2bf((v0.x - mu) * rstd * gg.x + bb.x);
        o.y = f2bf((v0.y - mu) * rstd * gg.y + bb.y);
        o.z = f2bf((v0.z - mu) * rstd * gg.z + bb.z);
        o.w = f2bf((v0.w - mu) * rstd * gg.w + bb.w);
        ((ushort4*)xo)[threadIdx.x] = o;
    }
    {
        const float4 gg = ((const float4*)g)[threadIdx.x + 256];
        const float4 bb = ((const float4*)b)[threadIdx.x + 256];
        ushort4 o;
        o.x = f2bf((v1.x - mu) * rstd * gg.x + bb.x);
        o.y = f2bf((v1.y - mu) * rstd * gg.y + bb.y);
        o.z = f2bf((v1.z - mu) * rstd * gg.z + bb.z);
        o.w = f2bf((v1.w - mu) * rstd * gg.w + bb.w);
        ((ushort4*)xo)[threadIdx.x + 256] = o;
    }
}

// ------------- weight transpose+cast: W[K][N] f32 -> Wt[N][K] bf16 -------------
__global__ __launch_bounds__(256) void wt_kernel(
        const float* __restrict__ W0, const float* __restrict__ W1,
        const float* __restrict__ W2, const float* __restrict__ W3,
        unsigned short* __restrict__ T0, unsigned short* __restrict__ T1,
        unsigned short* __restrict__ T2, unsigned short* __restrict__ T3) {
    const float* W; unsigned short* T;
    switch (blockIdx.z) {
        case 0:  W = W0; T = T0; break;
        case 1:  W = W1; T = T1; break;
        case 2:  W = W2; T = T2; break;
        default: W = W3; T = T3; break;
    }
    __shared__ float tile[32][33];
    const int tx = threadIdx.x & 31, ty = threadIdx.x >> 5;
    const int r0 = blockIdx.y * 32, c0 = blockIdx.x * 32;
    #pragma unroll
    for (int i = 0; i < 4; ++i)
        tile[ty + i * 8][tx] = W[(size_t)(r0 + ty + i * 8) * kDM + c0 + tx];
    __syncthreads();
    #pragma unroll
    for (int i = 0; i < 4; ++i)
        T[(size_t)(c0 + ty + i * 8) * kDM + r0 + tx] = f2bf(tile[tx][ty + i * 8]);
}

// --- bias concat: [bq|bk|bv] -> 6144 floats ---
__global__ __launch_bounds__(256) void bias_pack(const float* __restrict__ bq,
        const float* __restrict__ bk, const float* __restrict__ bv,
        float* __restrict__ o) {
    const int i = blockIdx.x * 256 + threadIdx.x;
    o[i] = (i < 2048) ? bq[i] : ((i < 4096) ? bk[i - 2048] : bv[i - 4096]);
}

// --- V transpose: [bh][s][dh] bf16 -> [bh][dh][s] bf16, 64x64 tiles ---
__global__ __launch_bounds__(256) void vtr_kernel(const unsigned short* __restrict__ Vin,
                                                  unsigned short* __restrict__ Vout) {
    __shared__ __align__(16) unsigned short tile[64 * 72];
    const int bhz = blockIdx.z;
    const int s0 = blockIdx.x * 64, d0 = blockIdx.y * 64;
    const int t = threadIdx.x;
    const unsigned short* src = Vin + ((size_t)bhz * kS + s0) * kDH + d0;
    #pragma unroll
    for (int i = 0; i < 2; ++i) {
        const int r = (t >> 3) + 32 * i;
        const int g = t & 7;
        *(uint4*)(tile + r * 72 + g * 8) = *(const uint4*)(src + (size_t)r * kDH + g * 8);
    }
    __syncthreads();
    unsigned short* dst = Vout + ((size_t)bhz * kDH + d0) * kS + s0;
    #pragma unroll
    for (int i = 0; i < 2; ++i) {
        const int d = (t >> 3) + 32 * i;
        const int sg = t & 7;
        union { unsigned short u[8]; uint4 v; } o;
        #pragma unroll
        for (int j = 0; j < 8; ++j)
            o.u[j] = tile[(sg * 8 + j) * 72 + d];
        *(uint4*)(dst + (size_t)d * kS + sg * 8) = o.v;
    }
}

// ------------- GEMM: C = A[M,K]bf16 @ Bt[N,K]^T bf16 + bias -------------
// LDS rows are 64B (4 x 16B granules); granule XOR-swizzled by ((row>>1)&3) so
// b128 fragment reads are 2-way max (free) instead of 8-way conflicted.
// fp32out=1: fp32 row-major to C0 (N<=2048).
// fp32out=0: bf16 [B,H,S,Dh] out; proj = n0>>11 selects C0/C1/C2; scale0 on proj 0.
__global__ __launch_bounds__(256) void gemm_kernel(
        const unsigned short* __restrict__ A, const unsigned short* __restrict__ Bt,
        const float* __restrict__ bias, void* __restrict__ C0, void* __restrict__ C1,
        void* __restrict__ C2, const float scale0, const int fp32out) {
    __shared__ __align__(16) unsigned short ldsA[128 * 32];
    __shared__ __align__(16) unsigned short ldsB[128 * 32];
    const int m0 = blockIdx.y * 128, n0 = blockIdx.x * 128;
    const int tid = threadIdx.x, lane = tid & 63, w = tid >> 6;
    const int wm = (w >> 1) * 64, wn = (w & 1) * 64;
    const int quad = lane >> 4, l15 = lane & 15;
    f32x4 acc[4][4] = {};
    const int srow = lane >> 2;
    const int scol = ((lane & 3) ^ ((srow >> 1) & 3)) * 8;   // source-side swizzle
    const int rswz = (l15 >> 1) & 3;                          // read-side swizzle
    for (int k0 = 0; k0 < kDM; k0 += 32) {
        __syncthreads();
        #pragma unroll
        for (int i = 0; i < 2; ++i) {
            const int c = w + i * 4;
            const int row = c * 16 + srow;
            load_lds16(A  + (size_t)(m0 + row) * kDM + k0 + scol, ldsA + c * 512);
            load_lds16(Bt + (size_t)(n0 + row) * kDM + k0 + scol, ldsB + c * 512);
        }
        __syncthreads();
        bf16x8 af[4], bfr[4];
        #pragma unroll
        for (int mt = 0; mt < 4; ++mt)
            af[mt] = *(const bf16x8*)(ldsA + (wm + mt * 16 + l15) * 32 + ((quad ^ rswz) << 3));
        #pragma unroll
        for (int nt = 0; nt < 4; ++nt)
            bfr[nt] = *(const bf16x8*)(ldsB + (wn + nt * 16 + l15) * 32 + ((quad ^ rswz) << 3));
        #pragma unroll
        for (int mt = 0; mt < 4; ++mt)
            #pragma unroll
            for (int nt = 0; nt < 4; ++nt)
                acc[mt][nt] = __builtin_amdgcn_mfma_f32_16x16x32_bf16(af[mt], bfr[nt], acc[mt][nt], 0, 0, 0);
    }
    const int proj = n0 >> 11;
    void* Cb = (proj == 0) ? C0 : ((proj == 1) ? C1 : C2);
    const float scl = (proj == 0) ? scale0 : 1.0f;
    #pragma unroll
    for (int mt = 0; mt < 4; ++mt) {
        #pragma unroll
        for (int nt = 0; nt < 4; ++nt) {
            const int ng = n0 + wn + nt * 16 + l15;
            const float bv = bias[ng];
            const int col = ng & 2047;
            const int h = col >> 7, dh = col & 127;
            #pragma unroll
            for (int r = 0; r < 4; ++r) {
                const int mg = m0 + wm + mt * 16 + quad * 4 + r;
                const float val = (acc[mt][nt][r] + bv) * scl;
                if (fp32out) {
                    ((float*)Cb)[(size_t)mg * kDM + ng] = val;
                } else {
                    const int bb = mg >> 11, ss = mg & 2047;
                    ((unsigned short*)Cb)[((size_t)(bb * kNH + h) * kS + ss) * kDH + dh] = f2bf(val);
                }
            }
        }
    }
}

// ------------- causal flash attention, S^T form, paired q-tiles -------------
// Q,K: [B,H,S,Dh] bf16 (Q pre-scaled by log2e/sqrt(Dh)); Vt: [B,H,Dh,S] bf16;
// AV out: [M, DM] bf16.  Block handles q-tiles pr and 31-pr (uniform 33 key-iters).
__global__ __launch_bounds__(256, 2) void attn_kernel(
        const unsigned short* __restrict__ Q, const unsigned short* __restrict__ Kk,
        const unsigned short* __restrict__ Vt, unsigned short* __restrict__ AV) {
    __shared__ __align__(16) unsigned short ldsK[64 * 128];   // swizzled [key][d]
    __shared__ __align__(16) unsigned short ldsV[128 * 64];   // swizzled [d][key]
    __shared__ __align__(16) unsigned short ldsP[4 * 16 * 64];// per-wave swizzled [q][key]
    const int bh = blockIdx.x, pr = blockIdx.y;
    const unsigned short* Qb = Q  + (size_t)bh * kS * kDH;
    const unsigned short* Kb = Kk + (size_t)bh * kS * kDH;
    const unsigned short* Vb = Vt + (size_t)bh * kDH * kS;
    const int tid = threadIdx.x, lane = tid & 63, w = tid >> 6;
    const int quad = lane >> 4, l15 = lane & 15;
    // staging offsets (source-swizzled so LDS layout is XOR-permuted)
    int kSrc[4], vSrc[4], ldst[4];
    #pragma unroll
    for (int i = 0; i < 4; ++i) {
        const int c = w * 4 + i;
        const int rK = c * 4 + (lane >> 4);
        const int gK = (lane & 15) ^ (rK & 15);
        kSrc[i] = rK * kDH + gK * 8;
        const int dV = c * 8 + (lane >> 3);
        const int gV = (lane & 7) ^ (dV & 7);
        vSrc[i] = dV * kS + gV * 8;
        ldst[i] = c * 512;
    }
    unsigned short* pw = ldsP + w * 1024;
    const int pswz = 2 * (l15 & 7);           // even XOR keeps 16B pairs intact
    const int bb = bh >> 4, h = bh & 15;
    for (int half = 0; half < 2; ++half) {
        const int qt = half ? (31 - pr) : pr;
        const int qrow0 = qt * 64 + w * 16;   // wave owns 16 q-rows
        bf16x8 qf[4];
        #pragma unroll
        for (int kk = 0; kk < 4; ++kk)
            qf[kk] = *(const bf16x8*)(Qb + (size_t)(qrow0 + l15) * kDH + kk * 32 + quad * 8);
        f32x4 accO[8] = {};
        float mrun = -3.0e38f, lrun = 0.0f;   // per-lane state for q = qrow0 + l15
        for (int kt = 0; kt <= qt; ++kt) {
            __syncthreads();
            #pragma unroll
            for (int i = 0; i < 4; ++i) {
                load_lds16(Kb + (size_t)kt * (64 * kDH) + kSrc[i], ldsK + ldst[i]);
                load_lds16(Vb + kt * 64 + vSrc[i], ldsV + ldst[i]);
            }
            __syncthreads();
            // S^T = K . Q^T : A = K-frag (m=key), B = Q-frag (n=q)
            f32x4 accS[4] = {};
            #pragma unroll
            for (int kk = 0; kk < 4; ++kk) {
                bf16x8 kf[4];
                #pragma unroll
                for (int mt = 0; mt < 4; ++mt)
                    kf[mt] = *(const bf16x8*)(ldsK + (mt * 16 + l15) * 128 + (((kk * 4 + quad) ^ l15) << 3));
                #pragma unroll
                for (int mt = 0; mt < 4; ++mt)
                    accS[mt] = __builtin_amdgcn_mfma_f32_16x16x32_bf16(kf[mt], qf[kk], accS[mt], 0, 0, 0);
            }
            if (kt == qt) {                   // diagonal: mask key_local > q_local
                const int ql = w * 16 + l15;
                #pragma unroll
                for (int mt = 0; mt < 4; ++mt)
                    #pragma unroll
                    for (int r = 0; r < 4; ++r)
                        if (mt * 16 + quad * 4 + r > ql) accS[mt][r] = -3.0e38f;
            }
            // per-lane softmax over 16 in-register keys + 2 cross-quad shuffles
            float mx = accS[0][0];
            #pragma unroll
            for (int mt = 0; mt < 4; ++mt)
                #pragma unroll
                for (int r = 0; r < 4; ++r) mx = fmaxf(mx, accS[mt][r]);
            mx = fmaxf(mx, __shfl_xor(mx, 16));
            mx = fmaxf(mx, __shfl_xor(mx, 32));
            const float mnew = fmaxf(mrun, mx);
            const float al = fast_exp2(mrun - mnew);
            float rs = 0.f;
            #pragma unroll
            for (int mt = 0; mt < 4; ++mt) {
                ushort4 pk;
                unsigned short* pe = (unsigned short*)&pk;
                #pragma unroll
                for (int r = 0; r < 4; ++r) {
                    const float p = fast_exp2(accS[mt][r] - mnew);
                    const unsigned short pb = f2bf(p);
                    pe[r] = pb;
                    rs += bf2f(pb);           // keep l consistent with bf16 P
                }
                *(ushort4*)(pw + l15 * 64 + (((mt * 4 + quad) ^ pswz) << 2)) = pk;
            }
            rs += __shfl_xor(rs, 16);
            rs += __shfl_xor(rs, 32);
            lrun = lrun * al + rs;
            mrun = mnew;
            // broadcast alpha from state-lane (l15 == quad*4+r) to accO rows
            float albr[4];
            #pragma unroll
            for (int r = 0; r < 4; ++r)
                albr[r] = __shfl(al, (lane & 48) | (quad << 2) | r);
            #pragma unroll
            for (int dt = 0; dt < 8; ++dt)
                #pragma unroll
                for (int r = 0; r < 4; ++r)
                    accO[dt][r] *= albr[r];
            asm volatile("s_waitcnt lgkmcnt(0)" ::: "memory");  // P writes visible to own wave
            // O += P . V : A = P-frag (m=q), B = V-frag (n=d)
            #pragma unroll
            for (int kk = 0; kk < 2; ++kk) {
                const bf16x8 pa = *(const bf16x8*)(pw + l15 * 64 + (((kk * 8 + quad * 2) ^ pswz) << 2));
                #pragma unroll
                for (int dt = 0; dt < 8; ++dt) {
                    const bf16x8 vf = *(const bf16x8*)(ldsV + (dt * 16 + l15) * 64 + (((kk * 4 + quad) ^ (l15 & 7)) << 3));
                    accO[dt] = __builtin_amdgcn_mfma_f32_16x16x32_bf16(pa, vf, accO[dt], 0, 0, 0);
                }
            }
        }
        float linv[4];
        #pragma unroll
        for (int r = 0; r < 4; ++r)
            linv[r] = __shfl(lrun, (lane & 48) | (quad << 2) | r);
        #pragma unroll
        for (int r = 0; r < 4; ++r) {
            const float inv = 1.0f / linv[r];
            unsigned short* orow = AV + ((size_t)bb * kS + qrow0 + quad * 4 + r) * kDM + h * kDH;
            #pragma unroll
            for (int dt = 0; dt < 8; ++dt)
                orow[dt * 16 + l15] = f2bf(accO[dt][r] * inv);
        }
    }
}

extern "C" void kernel_launch(void* const* d_in, const int* in_sizes, int n_in,
                              void* d_out, int out_size, void* d_ws, size_t ws_size,
                              hipStream_t stream) {
    const float* X   = (const float*)d_in[0];
    const float* lng = (const float*)d_in[1];
    const float* lnb = (const float*)d_in[2];
    const float* Wq  = (const float*)d_in[3];
    const float* bq  = (const float*)d_in[4];
    const float* Wk  = (const float*)d_in[5];
    const float* bk  = (const float*)d_in[6];
    const float* Wv  = (const float*)d_in[7];
    const float* bv  = (const float*)d_in[8];
    const float* Wo  = (const float*)d_in[9];
    const float* bo  = (const float*)d_in[10];
    float* out = (float*)d_out;

    char* p = (char*)d_ws;
    unsigned short* Xn  = (unsigned short*)p; p += (size_t)kM * kDM * 2;
    unsigned short* Wqt = (unsigned short*)p; p += (size_t)kDM * kDM * 2;  // Wq|Wk|Wv contiguous
    unsigned short* Wkt = (unsigned short*)p; p += (size_t)kDM * kDM * 2;
    unsigned short* Wvt = (unsigned short*)p; p += (size_t)kDM * kDM * 2;
    unsigned short* Wot = (unsigned short*)p; p += (size_t)kDM * kDM * 2;
    unsigned short* Qb  = (unsigned short*)p; p += (size_t)kM * kDM * 2;
    unsigned short* Kb  = (unsigned short*)p; p += (size_t)kM * kDM * 2;
    unsigned short* Vtb = (unsigned short*)p; p += (size_t)kM * kDM * 2;
    unsigned short* AV  = (unsigned short*)p; p += (size_t)kM * kDM * 2;
    unsigned short* Vtmp = AV;        // alias: consumed by vtr before attn writes AV
    float* biasc = (float*)Vtb;       // alias: consumed by qkv-gemm before vtr writes Vtb

    // log2(e)/sqrt(Dh): exp2-domain softmax
    const float qscale = 0.08838834764831845f * 1.4426950408889634f;

    ln_kernel<<<dim3(kM), dim3(256), 0, stream>>>(X, lng, lnb, Xn);
    wt_kernel<<<dim3(64, 64, 4), dim3(256), 0, stream>>>(Wq, Wk, Wv, Wo, Wqt, Wkt, Wvt, Wot);
    bias_pack<<<dim3(24), dim3(256), 0, stream>>>(bq, bk, bv, biasc);
    // fused QKV GEMM: N = 6144 over concatenated [Wqt|Wkt|Wvt]
    gemm_kernel<<<dim3(48, 32), dim3(256), 0, stream>>>(Xn, Wqt, biasc, Qb, Kb, Vtmp, qscale, 0);
    vtr_kernel<<<dim3(32, 2, 32), dim3(256), 0, stream>>>(Vtmp, Vtb);
    attn_kernel<<<dim3(32, 16), dim3(256), 0, stream>>>(Qb, Kb, Vtb, AV);
    gemm_kernel<<<dim3(16, 32), dim3(256), 0, stream>>>(AV, Wot, bo, out, out, out, 1.0f, 1);
}

// Round 5
// 391.864 us; speedup vs baseline: 1.5806x; 1.0052x over previous
//
#include <hip/hip_runtime.h>
#include <cstdint>

constexpr int kDM = 2048;   // d_model
constexpr int kNH = 16;     // heads
constexpr int kDH = 128;    // head dim
constexpr int kS  = 2048;   // seq
constexpr int kM  = 4096;   // B*S rows

typedef __bf16 bf16x8 __attribute__((ext_vector_type(8)));
typedef float  f32x4  __attribute__((ext_vector_type(4)));

__device__ __forceinline__ unsigned short f2bf(float f) {
    union { float f; unsigned u; } v; v.f = f;
    unsigned u = v.u;
    u += 0x7fffu + ((u >> 16) & 1u);   // RNE
    return (unsigned short)(u >> 16);
}
__device__ __forceinline__ float bf2f(unsigned short b) {
    union { unsigned u; float f; } v; v.u = ((unsigned)b) << 16;
    return v.f;
}
__device__ __forceinline__ float fast_exp2(float x) {
#if __has_builtin(__builtin_amdgcn_exp2f)
    return __builtin_amdgcn_exp2f(x);
#else
    return exp2f(x);
#endif
}
// async global->LDS, 16B per lane, LDS dest = wave-uniform base + lane*16
__device__ __forceinline__ void load_lds16(const void* g, void* l) {
    auto gp = (__attribute__((address_space(1))) unsigned int*)(uintptr_t)g;
    auto lp = (__attribute__((address_space(3))) unsigned int*)(uintptr_t)l;
    __builtin_amdgcn_global_load_lds(gp, lp, 16, 0, 0);
}

// ---------------- LayerNorm: fp32 in -> bf16 out ----------------
__global__ __launch_bounds__(256) void ln_kernel(const float* __restrict__ X,
        const float* __restrict__ g, const float* __restrict__ b,
        unsigned short* __restrict__ Xn) {
    const int row = blockIdx.x;
    const float* xr = X + (size_t)row * kDM;
    const float4 v0 = ((const float4*)xr)[threadIdx.x];
    const float4 v1 = ((const float4*)xr)[threadIdx.x + 256];
    float s  = v0.x + v0.y + v0.z + v0.w + v1.x + v1.y + v1.z + v1.w;
    float sq = v0.x*v0.x + v0.y*v0.y + v0.z*v0.z + v0.w*v0.w
             + v1.x*v1.x + v1.y*v1.y + v1.z*v1.z + v1.w*v1.w;
    #pragma unroll
    for (int m = 1; m < 64; m <<= 1) { s += __shfl_xor(s, m); sq += __shfl_xor(sq, m); }
    __shared__ float ls[4], lq[4];
    if ((threadIdx.x & 63) == 0) { ls[threadIdx.x >> 6] = s; lq[threadIdx.x >> 6] = sq; }
    __syncthreads();
    s  = ls[0] + ls[1] + ls[2] + ls[3];
    sq = lq[0] + lq[1] + lq[2] + lq[3];
    const float mu   = s * (1.0f / kDM);
    const float rstd = rsqrtf(sq * (1.0f / kDM) - mu * mu + 1e-5f);
    unsigned short* xo = Xn + (size_t)row * kDM;
    {
        const float4 gg = ((const float4*)g)[threadIdx.x];
        const float4 bb = ((const float4*)b)[threadIdx.x];
        ushort4 o;
        o.x = f2bf((v0.x - mu) * rstd * gg.x + bb.x);
        o.y = f2bf((v0.y - mu) * rstd * gg.y + bb.y);
        o.z = f2bf((v0.z - mu) * rstd * gg.z + bb.z);
        o.w = f2bf((v0.w - mu) * rstd * gg.w + bb.w);
        ((ushort4*)xo)[threadIdx.x] = o;
    }
    {
        const float4 gg = ((const float4*)g)[threadIdx.x + 256];
        const float4 bb = ((const float4*)b)[threadIdx.x + 256];
        ushort4 o;
        o.x = f2bf((v1.x - mu) * rstd * gg.x + bb.x);
        o.y = f2bf((v1.y - mu) * rstd * gg.y + bb.y);
        o.z = f2bf((v1.z - mu) * rstd * gg.z + bb.z);
        o.w = f2bf((v1.w - mu) * rstd * gg.w + bb.w);
        ((ushort4*)xo)[threadIdx.x + 256] = o;
    }
}

// ------------- weight transpose+cast: W[K][N] f32 -> Wt[N][K] bf16 -------------
__global__ __launch_bounds__(256) void wt_kernel(
        const float* __restrict__ W0, const float* __restrict__ W1,
        const float* __restrict__ W2, const float* __restrict__ W3,
        unsigned short* __restrict__ T0, unsigned short* __restrict__ T1,
        unsigned short* __restrict__ T2, unsigned short* __restrict__ T3) {
    const float* W; unsigned short* T;
    switch (blockIdx.z) {
        case 0:  W = W0; T = T0; break;
        case 1:  W = W1; T = T1; break;
        case 2:  W = W2; T = T2; break;
        default: W = W3; T = T3; break;
    }
    __shared__ float tile[32][33];
    const int tx = threadIdx.x & 31, ty = threadIdx.x >> 5;
    const int r0 = blockIdx.y * 32, c0 = blockIdx.x * 32;
    #pragma unroll
    for (int i = 0; i < 4; ++i)
        tile[ty + i * 8][tx] = W[(size_t)(r0 + ty + i * 8) * kDM + c0 + tx];
    __syncthreads();
    #pragma unroll
    for (int i = 0; i < 4; ++i)
        T[(size_t)(c0 + ty + i * 8) * kDM + r0 + tx] = f2bf(tile[tx][ty + i * 8]);
}

// --- bias concat: [bq|bk|bv] -> 6144 floats ---
__global__ __launch_bounds__(256) void bias_pack(const float* __restrict__ bq,
        const float* __restrict__ bk, const float* __restrict__ bv,
        float* __restrict__ o) {
    const int i = blockIdx.x * 256 + threadIdx.x;
    o[i] = (i < 2048) ? bq[i] : ((i < 4096) ? bk[i - 2048] : bv[i - 4096]);
}

// --- V transpose: [bh][s][dh] bf16 -> [bh][dh][s] bf16, 64x64 tiles ---
__global__ __launch_bounds__(256) void vtr_kernel(const unsigned short* __restrict__ Vin,
                                                  unsigned short* __restrict__ Vout) {
    __shared__ __align__(16) unsigned short tile[64 * 72];
    const int bhz = blockIdx.z;
    const int s0 = blockIdx.x * 64, d0 = blockIdx.y * 64;
    const int t = threadIdx.x;
    const unsigned short* src = Vin + ((size_t)bhz * kS + s0) * kDH + d0;
    #pragma unroll
    for (int i = 0; i < 2; ++i) {
        const int r = (t >> 3) + 32 * i;
        const int g = t & 7;
        *(uint4*)(tile + r * 72 + g * 8) = *(const uint4*)(src + (size_t)r * kDH + g * 8);
    }
    __syncthreads();
    unsigned short* dst = Vout + ((size_t)bhz * kDH + d0) * kS + s0;
    #pragma unroll
    for (int i = 0; i < 2; ++i) {
        const int d = (t >> 3) + 32 * i;
        const int sg = t & 7;
        union { unsigned short u[8]; uint4 v; } o;
        #pragma unroll
        for (int j = 0; j < 8; ++j)
            o.u[j] = tile[(sg * 8 + j) * 72 + d];
        *(uint4*)(dst + (size_t)d * kS + sg * 8) = o.v;
    }
}

// ------------- GEMM: C = A[M,K]bf16 @ Bt[N,K]^T bf16 + bias -------------
// BK=64 via two 32-k sub-buffers (half the barrier count vs BK=32); staging is
// ascending-contiguous per lane group (no source swizzle -- R4 showed that
// breaks VMEM coalescing and costs more than the LDS conflicts it removes).
// Grid: blockIdx.x = m-tile (fastest; B-column stays L2-hot), blockIdx.y = n-tile.
// fp32out=1: fp32 row-major to C0 (N<=2048).
// fp32out=0: bf16 [B,H,S,Dh] out; proj = n0>>11 selects C0/C1/C2; scale0 on proj 0.
__global__ __launch_bounds__(256) void gemm_kernel(
        const unsigned short* __restrict__ A, const unsigned short* __restrict__ Bt,
        const float* __restrict__ bias, void* __restrict__ C0, void* __restrict__ C1,
        void* __restrict__ C2, const float scale0, const int fp32out) {
    __shared__ __align__(16) unsigned short ldsA[2][128 * 32];
    __shared__ __align__(16) unsigned short ldsB[2][128 * 32];
    const int m0 = blockIdx.x * 128, n0 = blockIdx.y * 128;
    const int tid = threadIdx.x, lane = tid & 63, w = tid >> 6;
    const int wm = (w >> 1) * 64, wn = (w & 1) * 64;
    const int quad = lane >> 4, l15 = lane & 15;
    f32x4 acc[4][4] = {};
    const int srow = lane >> 2, scol = (lane & 3) * 8;
    for (int k0 = 0; k0 < kDM; k0 += 64) {
        __syncthreads();
        #pragma unroll
        for (int sub = 0; sub < 2; ++sub) {
            #pragma unroll
            for (int i = 0; i < 2; ++i) {
                const int c = w + i * 4;
                const int row = c * 16 + srow;
                const int kc = k0 + sub * 32 + scol;
                load_lds16(A  + (size_t)(m0 + row) * kDM + kc, &ldsA[sub][c * 512]);
                load_lds16(Bt + (size_t)(n0 + row) * kDM + kc, &ldsB[sub][c * 512]);
            }
        }
        __syncthreads();
        #pragma unroll
        for (int sub = 0; sub < 2; ++sub) {
            bf16x8 af[4], bfr[4];
            #pragma unroll
            for (int mt = 0; mt < 4; ++mt)
                af[mt] = *(const bf16x8*)(&ldsA[sub][(wm + mt * 16 + l15) * 32 + quad * 8]);
            #pragma unroll
            for (int nt = 0; nt < 4; ++nt)
                bfr[nt] = *(const bf16x8*)(&ldsB[sub][(wn + nt * 16 + l15) * 32 + quad * 8]);
            #pragma unroll
            for (int mt = 0; mt < 4; ++mt)
                #pragma unroll
                for (int nt = 0; nt < 4; ++nt)
                    acc[mt][nt] = __builtin_amdgcn_mfma_f32_16x16x32_bf16(af[mt], bfr[nt], acc[mt][nt], 0, 0, 0);
        }
    }
    const int proj = n0 >> 11;
    void* Cb = (proj == 0) ? C0 : ((proj == 1) ? C1 : C2);
    const float scl = (proj == 0) ? scale0 : 1.0f;
    #pragma unroll
    for (int mt = 0; mt < 4; ++mt) {
        #pragma unroll
        for (int nt = 0; nt < 4; ++nt) {
            const int ng = n0 + wn + nt * 16 + l15;
            const float bv = bias[ng];
            const int col = ng & 2047;
            const int h = col >> 7, dh = col & 127;
            #pragma unroll
            for (int r = 0; r < 4; ++r) {
                const int mg = m0 + wm + mt * 16 + quad * 4 + r;
                const float val = (acc[mt][nt][r] + bv) * scl;
                if (fp32out) {
                    ((float*)Cb)[(size_t)mg * kDM + ng] = val;
                } else {
                    const int bb = mg >> 11, ss = mg & 2047;
                    ((unsigned short*)Cb)[((size_t)(bb * kNH + h) * kS + ss) * kDH + dh] = f2bf(val);
                }
            }
        }
    }
}

// ------------- causal flash attention, S^T form, paired q-tiles -------------
// Q,K: [B,H,S,Dh] bf16 (Q pre-scaled by log2e/sqrt(Dh)); Vt: [B,H,Dh,S] bf16;
// AV out: [M, DM] bf16.  Block handles q-tiles pr and 31-pr (uniform 33 key-iters).
__global__ __launch_bounds__(256, 2) void attn_kernel(
        const unsigned short* __restrict__ Q, const unsigned short* __restrict__ Kk,
        const unsigned short* __restrict__ Vt, unsigned short* __restrict__ AV) {
    __shared__ __align__(16) unsigned short ldsK[64 * 128];   // swizzled [key][d]
    __shared__ __align__(16) unsigned short ldsV[128 * 64];   // swizzled [d][key]
    __shared__ __align__(16) unsigned short ldsP[4 * 16 * 64];// per-wave swizzled [q][key]
    const int bh = blockIdx.x, pr = blockIdx.y;
    const unsigned short* Qb = Q  + (size_t)bh * kS * kDH;
    const unsigned short* Kb = Kk + (size_t)bh * kS * kDH;
    const unsigned short* Vb = Vt + (size_t)bh * kDH * kS;
    const int tid = threadIdx.x, lane = tid & 63, w = tid >> 6;
    const int quad = lane >> 4, l15 = lane & 15;
    // staging offsets (source-swizzled so LDS layout is XOR-permuted)
    int kSrc[4], vSrc[4], ldst[4];
    #pragma unroll
    for (int i = 0; i < 4; ++i) {
        const int c = w * 4 + i;
        const int rK = c * 4 + (lane >> 4);
        const int gK = (lane & 15) ^ (rK & 15);
        kSrc[i] = rK * kDH + gK * 8;
        const int dV = c * 8 + (lane >> 3);
        const int gV = (lane & 7) ^ (dV & 7);
        vSrc[i] = dV * kS + gV * 8;
        ldst[i] = c * 512;
    }
    unsigned short* pw = ldsP + w * 1024;
    const int pswz = 2 * (l15 & 7);           // even XOR keeps 16B pairs intact
    const int bb = bh >> 4, h = bh & 15;
    for (int half = 0; half < 2; ++half) {
        const int qt = half ? (31 - pr) : pr;
        const int qrow0 = qt * 64 + w * 16;   // wave owns 16 q-rows
        bf16x8 qf[4];
        #pragma unroll
        for (int kk = 0; kk < 4; ++kk)
            qf[kk] = *(const bf16x8*)(Qb + (size_t)(qrow0 + l15) * kDH + kk * 32 + quad * 8);
        f32x4 accO[8] = {};
        float mrun = -3.0e38f, lrun = 0.0f;   // per-lane state for q = qrow0 + l15
        for (int kt = 0; kt <= qt; ++kt) {
            __syncthreads();
            #pragma unroll
            for (int i = 0; i < 4; ++i) {
                load_lds16(Kb + (size_t)kt * (64 * kDH) + kSrc[i], ldsK + ldst[i]);
                load_lds16(Vb + kt * 64 + vSrc[i], ldsV + ldst[i]);
            }
            __syncthreads();
            // S^T = K . Q^T : A = K-frag (m=key), B = Q-frag (n=q)
            f32x4 accS[4] = {};
            #pragma unroll
            for (int kk = 0; kk < 4; ++kk) {
                bf16x8 kf[4];
                #pragma unroll
                for (int mt = 0; mt < 4; ++mt)
                    kf[mt] = *(const bf16x8*)(ldsK + (mt * 16 + l15) * 128 + (((kk * 4 + quad) ^ l15) << 3));
                #pragma unroll
                for (int mt = 0; mt < 4; ++mt)
                    accS[mt] = __builtin_amdgcn_mfma_f32_16x16x32_bf16(kf[mt], qf[kk], accS[mt], 0, 0, 0);
            }
            if (kt == qt) {                   // diagonal: mask key_local > q_local
                const int ql = w * 16 + l15;
                #pragma unroll
                for (int mt = 0; mt < 4; ++mt)
                    #pragma unroll
                    for (int r = 0; r < 4; ++r)
                        if (mt * 16 + quad * 4 + r > ql) accS[mt][r] = -3.0e38f;
            }
            // per-lane softmax over 16 in-register keys + 2 cross-quad shuffles
            float mx = accS[0][0];
            #pragma unroll
            for (int mt = 0; mt < 4; ++mt)
                #pragma unroll
                for (int r = 0; r < 4; ++r) mx = fmaxf(mx, accS[mt][r]);
            mx = fmaxf(mx, __shfl_xor(mx, 16));
            mx = fmaxf(mx, __shfl_xor(mx, 32));
            const float mnew = fmaxf(mrun, mx);
            const float al = fast_exp2(mrun - mnew);
            float rs = 0.f;
            #pragma unroll
            for (int mt = 0; mt < 4; ++mt) {
                ushort4 pk;
                unsigned short* pe = (unsigned short*)&pk;
                #pragma unroll
                for (int r = 0; r < 4; ++r) {
                    const float p = fast_exp2(accS[mt][r] - mnew);
                    const unsigned short pb = f2bf(p);
                    pe[r] = pb;
                    rs += bf2f(pb);           // keep l consistent with bf16 P
                }
                *(ushort4*)(pw + l15 * 64 + (((mt * 4 + quad) ^ pswz) << 2)) = pk;
            }
            rs += __shfl_xor(rs, 16);
            rs += __shfl_xor(rs, 32);
            lrun = lrun * al + rs;
            mrun = mnew;
            // broadcast alpha from state-lane (l15 == quad*4+r) to accO rows
            float albr[4];
            #pragma unroll
            for (int r = 0; r < 4; ++r)
                albr[r] = __shfl(al, (lane & 48) | (quad << 2) | r);
            #pragma unroll
            for (int dt = 0; dt < 8; ++dt)
                #pragma unroll
                for (int r = 0; r < 4; ++r)
                    accO[dt][r] *= albr[r];
            asm volatile("s_waitcnt lgkmcnt(0)" ::: "memory");  // P writes visible to own wave
            // O += P . V : A = P-frag (m=q), B = V-frag (n=d)
            #pragma unroll
            for (int kk = 0; kk < 2; ++kk) {
                const bf16x8 pa = *(const bf16x8*)(pw + l15 * 64 + (((kk * 8 + quad * 2) ^ pswz) << 2));
                #pragma unroll
                for (int dt = 0; dt < 8; ++dt) {
                    const bf16x8 vf = *(const bf16x8*)(ldsV + (dt * 16 + l15) * 64 + (((kk * 4 + quad) ^ (l15 & 7)) << 3));
                    accO[dt] = __builtin_amdgcn_mfma_f32_16x16x32_bf16(pa, vf, accO[dt], 0, 0, 0);
                }
            }
        }
        float linv[4];
        #pragma unroll
        for (int r = 0; r < 4; ++r)
            linv[r] = __shfl(lrun, (lane & 48) | (quad << 2) | r);
        #pragma unroll
        for (int r = 0; r < 4; ++r) {
            const float inv = 1.0f / linv[r];
            unsigned short* orow = AV + ((size_t)bb * kS + qrow0 + quad * 4 + r) * kDM + h * kDH;
            #pragma unroll
            for (int dt = 0; dt < 8; ++dt)
                orow[dt * 16 + l15] = f2bf(accO[dt][r] * inv);
        }
    }
}

extern "C" void kernel_launch(void* const* d_in, const int* in_sizes, int n_in,
                              void* d_out, int out_size, void* d_ws, size_t ws_size,
                              hipStream_t stream) {
    const float* X   = (const float*)d_in[0];
    const float* lng = (const float*)d_in[1];
    const float* lnb = (const float*)d_in[2];
    const float* Wq  = (const float*)d_in[3];
    const float* bq  = (const float*)d_in[4];
    const float* Wk  = (const float*)d_in[5];
    const float* bk  = (const float*)d_in[6];
    const float* Wv  = (const float*)d_in[7];
    const float* bv  = (const float*)d_in[8];
    const float* Wo  = (const float*)d_in[9];
    const float* bo  = (const float*)d_in[10];
    float* out = (float*)d_out;

    char* p = (char*)d_ws;
    unsigned short* Xn  = (unsigned short*)p; p += (size_t)kM * kDM * 2;
    unsigned short* Wqt = (unsigned short*)p; p += (size_t)kDM * kDM * 2;  // Wq|Wk|Wv contiguous
    unsigned short* Wkt = (unsigned short*)p; p += (size_t)kDM * kDM * 2;
    unsigned short* Wvt = (unsigned short*)p; p += (size_t)kDM * kDM * 2;
    unsigned short* Wot = (unsigned short*)p; p += (size_t)kDM * kDM * 2;
    unsigned short* Qb  = (unsigned short*)p; p += (size_t)kM * kDM * 2;
    unsigned short* Kb  = (unsigned short*)p; p += (size_t)kM * kDM * 2;
    unsigned short* Vtb = (unsigned short*)p; p += (size_t)kM * kDM * 2;
    unsigned short* AV  = (unsigned short*)p; p += (size_t)kM * kDM * 2;
    unsigned short* Vtmp = AV;        // alias: consumed by vtr before attn writes AV
    float* biasc = (float*)Vtb;       // alias: consumed by qkv-gemm before vtr writes Vtb

    // log2(e)/sqrt(Dh): exp2-domain softmax
    const float qscale = 0.08838834764831845f * 1.4426950408889634f;

    ln_kernel<<<dim3(kM), dim3(256), 0, stream>>>(X, lng, lnb, Xn);
    wt_kernel<<<dim3(64, 64, 4), dim3(256), 0, stream>>>(Wq, Wk, Wv, Wo, Wqt, Wkt, Wvt, Wot);
    bias_pack<<<dim3(24), dim3(256), 0, stream>>>(bq, bk, bv, biasc);
    // fused QKV GEMM: N = 6144 over concatenated [Wqt|Wkt|Wvt]; m-tile fastest
    gemm_kernel<<<dim3(32, 48), dim3(256), 0, stream>>>(Xn, Wqt, biasc, Qb, Kb, Vtmp, qscale, 0);
    vtr_kernel<<<dim3(32, 2, 32), dim3(256), 0, stream>>>(Vtmp, Vtb);
    attn_kernel<<<dim3(32, 16), dim3(256), 0, stream>>>(Qb, Kb, Vtb, AV);
    gemm_kernel<<<dim3(32, 16), dim3(256), 0, stream>>>(AV, Wot, bo, out, out, out, 1.0f, 1);
}